// Round 11
// baseline (287.049 us; speedup 1.0000x reference)
//
#include <hip/hip_runtime.h>
#include <math.h>

#define NN 100000
#define NE 1600000
#define HD 32
#define HH 16        // half channels
#define NG 64
#define NC 8

#define P 256        // partitions
#define PART 391     // nodes per partition; 391*256 = 100096 >= NN
#define SCAP 7000    // staging capacity per partition (Poisson(6250), +9 sigma)
#define CH 8192      // edges per k_bin block
#define NBIN ((NE + CH - 1) / CH)   // 196
#define GEMM0_BLOCKS (NN / 8)       // 12500
#define G16_BLOCKS ((NN * 4 + 255) / 256)  // 1563
#define POOL_BLOCKS (NN * 8 / 256)  // 3125

__device__ __forceinline__ float bf2f(unsigned short u) {
    return __uint_as_float(((unsigned int)u) << 16);
}
__device__ __forceinline__ unsigned short f2bf(float f) {
    unsigned int b = __float_as_uint(f);
    b = (b + 0x7FFFu + ((b >> 16) & 1u)) >> 16;  // RNE
    return (unsigned short)b;
}

// ---------- phase 1: bin edges into col-range partitions ----------
__global__ __launch_bounds__(256) void k_bin(const int* __restrict__ row,
                                             const int* __restrict__ col,
                                             const float* __restrict__ w,
                                             int* __restrict__ pcnt,
                                             uint2* __restrict__ staging) {
    __shared__ int scol[CH];   // 32 KB
    __shared__ int hist[P];
    __shared__ int base_[P];
    int tid = threadIdx.x;
    int e0 = blockIdx.x * CH;
    int nrem = min(CH, NE - e0);
    hist[tid] = 0;
    __syncthreads();
    for (int i = tid; i < nrem; i += 256) {
        int c = col[e0 + i];
        scol[i] = c;
        atomicAdd(&hist[(unsigned)c / PART], 1);
    }
    __syncthreads();
    int h = hist[tid];
    base_[tid] = h ? atomicAdd(&pcnt[tid], h) : 0;
    __syncthreads();
    hist[tid] = 0;
    __syncthreads();
    for (int i = tid; i < nrem; i += 256) {
        int c = scol[i];
        int p = (unsigned)c / PART;
        int pos = base_[p] + atomicAdd(&hist[p], 1);
        uint2 v;
        v.x = (unsigned)(c - p * PART) | ((unsigned)row[e0 + i] << 9);
        v.y = __float_as_uint(w[e0 + i]);
        staging[(size_t)p * SCAP + pos] = v;
    }
}

// ---------- phase 2a (fused with gemm0): counts + dinv + CSR offsets || x@W1 ----------
__global__ __launch_bounds__(256) void k_csrA_gemm0(const int* __restrict__ pcnt,
                                                    const uint2* __restrict__ staging,
                                                    int* __restrict__ off,
                                                    int* __restrict__ cntg,
                                                    float* __restrict__ dinv,
                                                    const float* __restrict__ x,
                                                    const float* __restrict__ W1,
                                                    unsigned short* __restrict__ hlo,
                                                    unsigned short* __restrict__ hhi) {
    int tid = threadIdx.x;
    if (blockIdx.x < P) {
        __shared__ int spc[P];
        __shared__ int cnt_l[PART];
        __shared__ float wsum[PART];
        __shared__ int sc[PART];
        int p = blockIdx.x;
        spc[tid] = pcnt[tid];
        __syncthreads();
#pragma unroll
        for (int d = 1; d < P; d <<= 1) {
            int t = (tid >= d) ? spc[tid - d] : 0;
            __syncthreads();
            spc[tid] += t;
            __syncthreads();
        }
        int m = pcnt[p];
        int pb = (p > 0) ? spc[p - 1] : 0;
        for (int i = tid; i < PART; i += 256) { cnt_l[i] = 0; wsum[i] = 0.0f; }
        __syncthreads();
        const uint2* st = staging + (size_t)p * SCAP;
        for (int i = tid; i < m; i += 256) {
            uint2 v = st[i];
            int cl = v.x & 511;
            atomicAdd(&cnt_l[cl], 1);
            atomicAdd(&wsum[cl], __uint_as_float(v.y));
        }
        __syncthreads();
        for (int i = tid; i < PART; i += 256) sc[i] = cnt_l[i];
        __syncthreads();
        int i0 = tid, i1 = tid + 256;
#pragma unroll
        for (int d = 1; d < 512; d <<= 1) {
            int t0 = 0, t1 = 0;
            if (i0 < PART && i0 >= d) t0 = sc[i0 - d];
            if (i1 < PART && i1 >= d) t1 = sc[i1 - d];
            __syncthreads();
            if (i0 < PART) sc[i0] += t0;
            if (i1 < PART) sc[i1] += t1;
            __syncthreads();
        }
        for (int i = tid; i < PART; i += 256) {
            int n = p * PART + i;
            if (n < NN) {
                off[n] = pb + sc[i] - cnt_l[i];
                cntg[n] = cnt_l[i];
                dinv[n] = rsqrtf(1.0f + wsum[i]);
            }
        }
    } else {
        __shared__ float sW[32 * 32];
        __shared__ float sX[8 * 32];
        int base = (blockIdx.x - P) * 8;
        ((float4*)sW)[tid] = ((const float4*)W1)[tid];
        if (tid < 64) ((float4*)sX)[tid] = ((const float4*)(x + (size_t)base * 32))[tid];
        __syncthreads();
        int c = tid & 31, nl = tid >> 5;
        float acc = 0.0f;
#pragma unroll
        for (int k = 0; k < 32; ++k) acc = fmaf(sX[nl * 32 + k], sW[k * 32 + c], acc);
        unsigned short hb = f2bf(acc);
        int n = base + nl;
        if (c < HH) hlo[(size_t)n * HH + c] = hb;
        else        hhi[(size_t)n * HH + (c - HH)] = hb;
    }
}

// ---------- phase 2b: write final normalized pairs ----------
__global__ __launch_bounds__(512) void k_csr_b(const int* __restrict__ pcnt,
                                               const uint2* __restrict__ staging,
                                               const int* __restrict__ off,
                                               const float* __restrict__ dinv,
                                               float2* __restrict__ pairs) {
    __shared__ int cur[PART];
    __shared__ float sdc[PART];
    int p = blockIdx.x, tid = threadIdx.x;
    int m = pcnt[p];
    const uint2* st = staging + (size_t)p * SCAP;
    for (int i = tid; i < PART; i += 512) {
        int n = p * PART + i;
        cur[i] = (n < NN) ? off[n] : 0;
        sdc[i] = (n < NN) ? dinv[n] : 0.0f;
    }
    __syncthreads();
    for (int ib = tid; ib < m; ib += 512 * 4) {
        uint2 v[4];
        float dr[4];
#pragma unroll
        for (int j = 0; j < 4; ++j) {
            int i = ib + j * 512;
            if (i < m) v[j] = st[i];
        }
#pragma unroll
        for (int j = 0; j < 4; ++j) {
            int i = ib + j * 512;
            if (i < m) dr[j] = dinv[v[j].x >> 9];
        }
#pragma unroll
        for (int j = 0; j < 4; ++j) {
            int i = ib + j * 512;
            if (i < m) {
                int cl = v[j].x & 511;
                int pos = atomicAdd(&cur[cl], 1);
                float y = dr[j] * __uint_as_float(v[j].y) * sdc[cl];
                pairs[pos] = make_float2(__int_as_float((int)(v[j].x >> 9)), y);
            }
        }
    }
}

// ---------- half-channel gather: agg[n,0:16] = dinv^2*h[n] + sum nrm*h[r] ----------
// h half = NN x 16 bf16 (3.2 MB, per-XCD-L2-resident); pairs nontemporal.
__global__ __launch_bounds__(256) void k_g16(const unsigned short* __restrict__ hb,
                                             const int* __restrict__ off,
                                             const int* __restrict__ cntg,
                                             const float* __restrict__ dinv,
                                             const float2* __restrict__ pairs,
                                             float* __restrict__ agg) {
    int t = blockIdx.x * 256 + threadIdx.x;  // over NN*4 (padded)
    int n = t >> 2, c4 = t & 3;
    if (n >= NN) return;
    int cn = cntg[n];
    const unsigned long long* pp = (const unsigned long long*)(pairs + off[n]);
    float di = dinv[n], sl = di * di;
    ushort4 hu = *((const ushort4*)(hb + (size_t)n * HH) + c4);
    float4 acc = make_float4(sl * bf2f(hu.x), sl * bf2f(hu.y),
                             sl * bf2f(hu.z), sl * bf2f(hu.w));
    int k = 0;
    for (; k + 8 <= cn; k += 8) {
        unsigned long long p[8];
#pragma unroll
        for (int j = 0; j < 8; ++j) p[j] = __builtin_nontemporal_load(pp + k + j);
        ushort4 v[8];
#pragma unroll
        for (int j = 0; j < 8; ++j)
            v[j] = *((const ushort4*)(hb + (size_t)(unsigned)(p[j] & 0xffffffffu) * HH) + c4);
#pragma unroll
        for (int j = 0; j < 8; ++j) {
            float nm = __uint_as_float((unsigned)(p[j] >> 32));
            acc.x = fmaf(nm, bf2f(v[j].x), acc.x);
            acc.y = fmaf(nm, bf2f(v[j].y), acc.y);
            acc.z = fmaf(nm, bf2f(v[j].z), acc.z);
            acc.w = fmaf(nm, bf2f(v[j].w), acc.w);
        }
    }
    for (; k + 4 <= cn; k += 4) {
        unsigned long long p[4];
#pragma unroll
        for (int j = 0; j < 4; ++j) p[j] = __builtin_nontemporal_load(pp + k + j);
        ushort4 v[4];
#pragma unroll
        for (int j = 0; j < 4; ++j)
            v[j] = *((const ushort4*)(hb + (size_t)(unsigned)(p[j] & 0xffffffffu) * HH) + c4);
#pragma unroll
        for (int j = 0; j < 4; ++j) {
            float nm = __uint_as_float((unsigned)(p[j] >> 32));
            acc.x = fmaf(nm, bf2f(v[j].x), acc.x);
            acc.y = fmaf(nm, bf2f(v[j].y), acc.y);
            acc.z = fmaf(nm, bf2f(v[j].z), acc.z);
            acc.w = fmaf(nm, bf2f(v[j].w), acc.w);
        }
    }
    for (; k < cn; ++k) {
        unsigned long long p = __builtin_nontemporal_load(pp + k);
        ushort4 v = *((const ushort4*)(hb + (size_t)(unsigned)(p & 0xffffffffu) * HH) + c4);
        float nm = __uint_as_float((unsigned)(p >> 32));
        acc.x = fmaf(nm, bf2f(v.x), acc.x);
        acc.y = fmaf(nm, bf2f(v.y), acc.y);
        acc.z = fmaf(nm, bf2f(v.z), acc.z);
        acc.w = fmaf(nm, bf2f(v.w), acc.w);
    }
    *((float4*)(agg + (size_t)n * HH) + c4) = acc;
}

// ---------- transform: h_next = split_bf16( relu(agg + bias) @ Wn ) ----------
__global__ __launch_bounds__(256) void k_transform(const float* __restrict__ aggLo,
                                                   const float* __restrict__ aggHi,
                                                   const float* __restrict__ bias,
                                                   const float* __restrict__ Wn,
                                                   unsigned short* __restrict__ hlo,
                                                   unsigned short* __restrict__ hhi) {
    __shared__ float sW[32 * 32];
    __shared__ float sX[8 * 32];
    int tid = threadIdx.x;
    int base = blockIdx.x * 8;
    ((float4*)sW)[tid] = ((const float4*)Wn)[tid];
    if (tid < 64) {
        int nl = tid >> 3, j = tid & 7;
        int n = base + nl;
        float4 v;
        int cb;
        if (j < 4) { cb = j * 4;            v = *((const float4*)(aggLo + (size_t)n * HH) + j); }
        else       { cb = 16 + (j - 4) * 4; v = *((const float4*)(aggHi + (size_t)n * HH) + (j - 4)); }
        v.x = fmaxf(v.x + bias[cb + 0], 0.0f);
        v.y = fmaxf(v.y + bias[cb + 1], 0.0f);
        v.z = fmaxf(v.z + bias[cb + 2], 0.0f);
        v.w = fmaxf(v.w + bias[cb + 3], 0.0f);
        *((float4*)(sX + nl * 32 + cb)) = v;
    }
    __syncthreads();
    int c = tid & 31, nl = tid >> 5;
    float acc = 0.0f;
#pragma unroll
    for (int k = 0; k < 32; ++k) acc = fmaf(sX[nl * 32 + k], sW[k * 32 + c], acc);
    unsigned short hb = f2bf(acc);
    int n = base + nl;
    if (c < HH) hlo[(size_t)n * HH + c] = hb;
    else        hhi[(size_t)n * HH + (c - HH)] = hb;
}

// ---------- fused pool: relu(agg + b3) block-reduced by graph into gsum/gcnt ----------
__global__ __launch_bounds__(256) void k_pool(const float* __restrict__ aggLo,
                                              const float* __restrict__ aggHi,
                                              const float* __restrict__ b3,
                                              const int* __restrict__ batch,
                                              float* __restrict__ gsum,
                                              float* __restrict__ gcnt) {
    __shared__ float psum[4 * 33];
    __shared__ float pcl[4];
    int tid = threadIdx.x;
    if (tid < 132) psum[tid] = 0.0f;
    if (tid < 4) pcl[tid] = 0.0f;
    int t = blockIdx.x * 256 + tid;  // NN*8 exact
    int n = t >> 3, c4 = t & 7;
    int cb = c4 * 4;
    float4 v = (c4 < 4) ? *((const float4*)(aggLo + (size_t)n * HH) + c4)
                        : *((const float4*)(aggHi + (size_t)n * HH) + (c4 - 4));
    float r0 = fmaxf(v.x + b3[cb + 0], 0.0f);
    float r1 = fmaxf(v.y + b3[cb + 1], 0.0f);
    float r2 = fmaxf(v.z + b3[cb + 2], 0.0f);
    float r3 = fmaxf(v.w + b3[cb + 3], 0.0f);
    int gmin = batch[blockIdx.x * 32];
    int slot = min(batch[n] - gmin, 3);
    __syncthreads();
    atomicAdd(&psum[slot * 33 + cb + 0], r0);
    atomicAdd(&psum[slot * 33 + cb + 1], r1);
    atomicAdd(&psum[slot * 33 + cb + 2], r2);
    atomicAdd(&psum[slot * 33 + cb + 3], r3);
    if (c4 == 0) atomicAdd(&pcl[slot], 1.0f);
    __syncthreads();
    if (tid < 128) {
        int s = tid >> 5, c = tid & 31;
        float vv = psum[s * 33 + c];
        if (vv != 0.0f && gmin + s < NG) atomicAdd(&gsum[(gmin + s) * HD + c], vv);
    }
    if (tid < 4 && pcl[tid] > 0.0f && gmin + tid < NG)
        atomicAdd(&gcnt[gmin + tid], pcl[tid]);
}

// ---------- head ----------
__global__ __launch_bounds__(256) void k_head(const float* __restrict__ gsum,
                                              const float* __restrict__ gcnt,
                                              const float* __restrict__ Wout,
                                              const float* __restrict__ bout,
                                              float* __restrict__ out) {
    __shared__ float pooled[NG * 33];
    __shared__ float sW[32 * NC];
    __shared__ float slog[NG * NC];
    int tid = threadIdx.x;
    sW[tid] = Wout[tid];  // 256 = 32*8
    for (int i = tid; i < NG * HD; i += 256) {
        int g = i >> 5, c = i & 31;
        pooled[g * 33 + c] = gsum[i] / fmaxf(gcnt[g], 1.0f);
    }
    __syncthreads();
    for (int i = tid; i < NG * NC; i += 256) {
        int g = i >> 3, c = i & 7;
        float l = bout[c];
        const float* pr = pooled + g * 33;
#pragma unroll
        for (int k = 0; k < 32; ++k) l = fmaf(pr[k], sW[k * NC + c], l);
        slog[i] = l;
    }
    __syncthreads();
    if (tid < NG) {
        const float* sl = slog + tid * NC;
        float m = sl[0];
#pragma unroll
        for (int i = 1; i < NC; ++i) m = fmaxf(m, sl[i]);
        float s = 0.0f;
#pragma unroll
        for (int i = 0; i < NC; ++i) s += expf(sl[i] - m);
        float lse = m + logf(s);
#pragma unroll
        for (int i = 0; i < NC; ++i) out[tid * NC + i] = sl[i] - lse;
    }
}

extern "C" void kernel_launch(void* const* d_in, const int* in_sizes, int n_in,
                              void* d_out, int out_size, void* d_ws, size_t ws_size,
                              hipStream_t stream) {
    const float* x     = (const float*)d_in[0];
    const int*   eidx  = (const int*)d_in[1];
    const float* ew    = (const float*)d_in[2];
    const int*   batch = (const int*)d_in[3];
    const float* W1 = (const float*)d_in[4];
    const float* b1 = (const float*)d_in[5];
    const float* W2 = (const float*)d_in[6];
    const float* b2 = (const float*)d_in[7];
    const float* W3 = (const float*)d_in[8];
    const float* b3 = (const float*)d_in[9];
    const float* Wout = (const float*)d_in[10];
    const float* bout = (const float*)d_in[11];
    float* out = (float*)d_out;

    const int* row = eidx;        // sources
    const int* col = eidx + NE;   // targets

    // layout: hA_lo|hA_hi|hB_lo|hB_hi (bf16 halves) | aggLo|aggHi (f32) | pairs | staging
    //         | dinv | off | cntg | [pcnt | gsum | gcnt] (zeroed)   ~54 MB
    unsigned short* hAlo = (unsigned short*)d_ws;                 // 3.2 MB
    unsigned short* hAhi = hAlo + (size_t)NN * HH;                // 3.2 MB
    unsigned short* hBlo = hAhi + (size_t)NN * HH;                // 3.2 MB
    unsigned short* hBhi = hBlo + (size_t)NN * HH;                // 3.2 MB
    float* aggLo = (float*)(hBhi + (size_t)NN * HH);              // 6.4 MB
    float* aggHi = aggLo + (size_t)NN * HH;                       // 6.4 MB
    float2* pairs = (float2*)(aggHi + (size_t)NN * HH);           // 12.8 MB
    uint2* staging = (uint2*)(pairs + NE);                        // 14.3 MB
    float* dinv = (float*)(staging + (size_t)P * SCAP);           // 0.4 MB
    int* off  = (int*)(dinv + NN);                                // 0.4 MB
    int* cntg = off + NN;                                         // 0.4 MB
    int* pcnt = cntg + NN;                                        // P ints
    float* gsum = (float*)(pcnt + P);                             // NG*HD
    float* gcnt = gsum + NG * HD;                                 // NG

    hipMemsetAsync(pcnt, 0, (P + NG * HD + NG) * sizeof(int), stream);
    k_bin<<<NBIN, 256, 0, stream>>>(row, col, ew, pcnt, staging);
    k_csrA_gemm0<<<P + GEMM0_BLOCKS, 256, 0, stream>>>(pcnt, staging, off, cntg, dinv,
                                                       x, W1, hAlo, hAhi);
    k_csr_b<<<P, 512, 0, stream>>>(pcnt, staging, off, dinv, pairs);

    // layer 1
    k_g16<<<G16_BLOCKS, 256, 0, stream>>>(hAlo, off, cntg, dinv, pairs, aggLo);
    k_g16<<<G16_BLOCKS, 256, 0, stream>>>(hAhi, off, cntg, dinv, pairs, aggHi);
    k_transform<<<GEMM0_BLOCKS, 256, 0, stream>>>(aggLo, aggHi, b1, W2, hBlo, hBhi);
    // layer 2
    k_g16<<<G16_BLOCKS, 256, 0, stream>>>(hBlo, off, cntg, dinv, pairs, aggLo);
    k_g16<<<G16_BLOCKS, 256, 0, stream>>>(hBhi, off, cntg, dinv, pairs, aggHi);
    k_transform<<<GEMM0_BLOCKS, 256, 0, stream>>>(aggLo, aggHi, b2, W3, hAlo, hAhi);
    // layer 3 + pool
    k_g16<<<G16_BLOCKS, 256, 0, stream>>>(hAlo, off, cntg, dinv, pairs, aggLo);
    k_g16<<<G16_BLOCKS, 256, 0, stream>>>(hAhi, off, cntg, dinv, pairs, aggHi);
    k_pool<<<POOL_BLOCKS, 256, 0, stream>>>(aggLo, aggHi, b3, batch, gsum, gcnt);
    k_head<<<1, 256, 0, stream>>>(gsum, gcnt, Wout, bout, out);
}

// Round 12
// 263.184 us; speedup vs baseline: 1.0907x; 1.0907x over previous
//
#include <hip/hip_runtime.h>
#include <math.h>

#define NN 100000
#define NE 1600000
#define HD 32
#define NG 64
#define NC 8

#define P 256        // partitions
#define PART 391     // nodes per partition; 391*256 = 100096 >= NN
#define SCAP 7000    // staging capacity per partition (Poisson(6250), +9 sigma)
#define CH 4096      // edges per k_bin block
#define NBIN ((NE + CH - 1) / CH)    // 391
#define NORM_BLOCKS (NN * 8 / 256)   // 3125 (gather grid)
#define GEMM0_BLOCKS (NN / 8)        // 12500

__device__ __forceinline__ float bf2f(unsigned short u) {
    return __uint_as_float(((unsigned int)u) << 16);
}
__device__ __forceinline__ unsigned short f2bf(float f) {
    unsigned int b = __float_as_uint(f);
    b = (b + 0x7FFFu + ((b >> 16) & 1u)) >> 16;  // RNE
    return (unsigned short)b;
}
// ---- fp8 e4m3fn helpers (manual; values clamped to +-448) ----
__device__ __forceinline__ float e4m3f(unsigned u) {
    unsigned code = u & 0x7fu;
    unsigned e = code >> 3;
    float v;
    if (e == 0) v = (float)code * 0.001953125f;  // m * 2^-9
    else v = __uint_as_float(((e + 120u) << 23) | ((code & 7u) << 20));
    return (u & 0x80u) ? -v : v;
}
__device__ __forceinline__ unsigned f2e4m3(float f) {
    unsigned s = (__float_as_uint(f) >> 31) << 7;
    float a = fminf(fabsf(f), 448.0f);
    unsigned code;
    if (a >= 0.015625f) {
        unsigned x = __float_as_uint(a);
        x += 0x0007FFFFu + ((x >> 20) & 1u);
        code = (((x >> 23) - 120u) << 3) | ((x >> 20) & 7u);
    } else {
        code = (unsigned)__float2int_rn(a * 512.0f);
    }
    return s | code;
}

// ---------- phase 1: bin edges into col-range partitions (1024 threads) ----------
// staging entry: x = col_lo | (row << 9), y = w bits
__global__ __launch_bounds__(1024) void k_bin(const int* __restrict__ row,
                                              const int* __restrict__ col,
                                              const float* __restrict__ w,
                                              int* __restrict__ pcnt,
                                              uint2* __restrict__ staging) {
    __shared__ int scol[CH];   // 16 KB
    __shared__ int hist[P];
    __shared__ int base_[P];
    int tid = threadIdx.x;
    int e0 = blockIdx.x * CH;
    int nrem = min(CH, NE - e0);
    if (tid < P) hist[tid] = 0;
    __syncthreads();
    for (int i = tid; i < nrem; i += 1024) {
        int c = col[e0 + i];
        scol[i] = c;
        atomicAdd(&hist[(unsigned)c / PART], 1);
    }
    __syncthreads();
    if (tid < P) {
        int h = hist[tid];
        base_[tid] = h ? atomicAdd(&pcnt[tid], h) : 0;
        hist[tid] = 0;
    }
    __syncthreads();
    for (int i = tid; i < nrem; i += 1024) {
        int c = scol[i];
        int p = (unsigned)c / PART;
        int pos = base_[p] + atomicAdd(&hist[p], 1);
        uint2 v;
        v.x = (unsigned)(c - p * PART) | ((unsigned)row[e0 + i] << 9);
        v.y = __float_as_uint(w[e0 + i]);
        staging[(size_t)p * SCAP + pos] = v;
    }
}

// ---------- phase 2a (fused with gemm0): counts + dinv + CSR offsets || h1 = fp8(x@W1) ----------
__global__ __launch_bounds__(256) void k_csrA_gemm0(const int* __restrict__ pcnt,
                                                    const uint2* __restrict__ staging,
                                                    int* __restrict__ off,
                                                    int* __restrict__ cntg,
                                                    float* __restrict__ dinv,
                                                    const float* __restrict__ x,
                                                    const float* __restrict__ W1,
                                                    unsigned char* __restrict__ h1) {
    int tid = threadIdx.x;
    if (blockIdx.x < P) {
        __shared__ int spc[P];
        __shared__ int cnt_l[PART];
        __shared__ float wsum[PART];
        __shared__ int sc[PART];
        int p = blockIdx.x;
        spc[tid] = pcnt[tid];
        __syncthreads();
#pragma unroll
        for (int d = 1; d < P; d <<= 1) {
            int t = (tid >= d) ? spc[tid - d] : 0;
            __syncthreads();
            spc[tid] += t;
            __syncthreads();
        }
        int m = pcnt[p];
        int pb = (p > 0) ? spc[p - 1] : 0;
        for (int i = tid; i < PART; i += 256) { cnt_l[i] = 0; wsum[i] = 0.0f; }
        __syncthreads();
        const uint2* st = staging + (size_t)p * SCAP;
        for (int i = tid; i < m; i += 256) {
            uint2 v = st[i];
            int cl = v.x & 511;
            atomicAdd(&cnt_l[cl], 1);
            atomicAdd(&wsum[cl], __uint_as_float(v.y));
        }
        __syncthreads();
        for (int i = tid; i < PART; i += 256) sc[i] = cnt_l[i];
        __syncthreads();
        int i0 = tid, i1 = tid + 256;
#pragma unroll
        for (int d = 1; d < 512; d <<= 1) {
            int t0 = 0, t1 = 0;
            if (i0 < PART && i0 >= d) t0 = sc[i0 - d];
            if (i1 < PART && i1 >= d) t1 = sc[i1 - d];
            __syncthreads();
            if (i0 < PART) sc[i0] += t0;
            if (i1 < PART) sc[i1] += t1;
            __syncthreads();
        }
        for (int i = tid; i < PART; i += 256) {
            int n = p * PART + i;
            if (n < NN) {
                off[n] = pb + sc[i] - cnt_l[i];
                cntg[n] = cnt_l[i];
                dinv[n] = rsqrtf(1.0f + wsum[i]);
            }
        }
    } else {
        __shared__ float sW[32 * 32];
        __shared__ float sX[8 * 32];
        int base = (blockIdx.x - P) * 8;
        ((float4*)sW)[tid] = ((const float4*)W1)[tid];
        if (tid < 64) ((float4*)sX)[tid] = ((const float4*)(x + (size_t)base * 32))[tid];
        __syncthreads();
        int c = tid & 31, nl = tid >> 5;
        float acc = 0.0f;
#pragma unroll
        for (int k = 0; k < 32; ++k) acc = fmaf(sX[nl * 32 + k], sW[k * 32 + c], acc);
        h1[(size_t)(base + nl) * 32 + c] = (unsigned char)f2e4m3(acc);
    }
}

// ---------- phase 2b: write final normalized pairs ----------
__global__ __launch_bounds__(512) void k_csr_b(const int* __restrict__ pcnt,
                                               const uint2* __restrict__ staging,
                                               const int* __restrict__ off,
                                               const float* __restrict__ dinv,
                                               float2* __restrict__ pairs) {
    __shared__ int cur[PART];
    __shared__ float sdc[PART];
    int p = blockIdx.x, tid = threadIdx.x;
    int m = pcnt[p];
    const uint2* st = staging + (size_t)p * SCAP;
    for (int i = tid; i < PART; i += 512) {
        int n = p * PART + i;
        cur[i] = (n < NN) ? off[n] : 0;
        sdc[i] = (n < NN) ? dinv[n] : 0.0f;
    }
    __syncthreads();
    for (int ib = tid; ib < m; ib += 512 * 4) {
        uint2 v[4];
        float dr[4];
#pragma unroll
        for (int j = 0; j < 4; ++j) {
            int i = ib + j * 512;
            if (i < m) v[j] = st[i];
        }
#pragma unroll
        for (int j = 0; j < 4; ++j) {
            int i = ib + j * 512;
            if (i < m) dr[j] = dinv[v[j].x >> 9];
        }
#pragma unroll
        for (int j = 0; j < 4; ++j) {
            int i = ib + j * 512;
            if (i < m) {
                int cl = v[j].x & 511;
                int pos = atomicAdd(&cur[cl], 1);
                float y = dr[j] * __uint_as_float(v[j].y) * sdc[cl];
                pairs[pos] = make_float2(__int_as_float((int)(v[j].x >> 9)), y);
            }
        }
    }
}

// ---------- gather (fp8 h): MODE 0 = fuse next GEMM (fp8 out), MODE 1 = bf16 relu out ----------
template <int MODE>
__global__ __launch_bounds__(256) void k_gather(const unsigned char* __restrict__ hb,
                                                const int* __restrict__ off,
                                                const int* __restrict__ cntg,
                                                const float* __restrict__ dinv,
                                                const float2* __restrict__ pairs,
                                                const float* __restrict__ bias,
                                                const float* __restrict__ Wn,
                                                unsigned char* __restrict__ hout,
                                                unsigned short* __restrict__ h3out) {
    __shared__ float sW[32 * 32];
    __shared__ float srow[32 * 33];
    int tid = threadIdx.x;
    if (MODE == 0) ((float4*)sW)[tid] = ((const float4*)Wn)[tid];
    int t = blockIdx.x * 256 + tid;  // NN*8 exact
    int n = t >> 3, c4 = t & 7;
    int cn = cntg[n];
    const unsigned long long* pp =
        (const unsigned long long*)(pairs + off[n]);
    float di = dinv[n], sl = di * di;
    unsigned hu = *(const unsigned*)(hb + (size_t)n * 32 + c4 * 4);
    float4 acc = make_float4(sl * e4m3f(hu & 255), sl * e4m3f((hu >> 8) & 255),
                             sl * e4m3f((hu >> 16) & 255), sl * e4m3f(hu >> 24));
    int k = 0;
    for (; k + 8 <= cn; k += 8) {
        unsigned long long p[8];
#pragma unroll
        for (int j = 0; j < 8; ++j) p[j] = __builtin_nontemporal_load(pp + k + j);
        unsigned v[8];
#pragma unroll
        for (int j = 0; j < 8; ++j)
            v[j] = *(const unsigned*)(hb + (size_t)(unsigned)(p[j] & 0xffffffffu) * 32 + c4 * 4);
#pragma unroll
        for (int j = 0; j < 8; ++j) {
            float nm = __uint_as_float((unsigned)(p[j] >> 32));
            acc.x = fmaf(nm, e4m3f(v[j] & 255), acc.x);
            acc.y = fmaf(nm, e4m3f((v[j] >> 8) & 255), acc.y);
            acc.z = fmaf(nm, e4m3f((v[j] >> 16) & 255), acc.z);
            acc.w = fmaf(nm, e4m3f(v[j] >> 24), acc.w);
        }
    }
    for (; k + 4 <= cn; k += 4) {
        unsigned long long p[4];
#pragma unroll
        for (int j = 0; j < 4; ++j) p[j] = __builtin_nontemporal_load(pp + k + j);
        unsigned v[4];
#pragma unroll
        for (int j = 0; j < 4; ++j)
            v[j] = *(const unsigned*)(hb + (size_t)(unsigned)(p[j] & 0xffffffffu) * 32 + c4 * 4);
#pragma unroll
        for (int j = 0; j < 4; ++j) {
            float nm = __uint_as_float((unsigned)(p[j] >> 32));
            acc.x = fmaf(nm, e4m3f(v[j] & 255), acc.x);
            acc.y = fmaf(nm, e4m3f((v[j] >> 8) & 255), acc.y);
            acc.z = fmaf(nm, e4m3f((v[j] >> 16) & 255), acc.z);
            acc.w = fmaf(nm, e4m3f(v[j] >> 24), acc.w);
        }
    }
    for (; k < cn; ++k) {
        unsigned long long p = __builtin_nontemporal_load(pp + k);
        unsigned v = *(const unsigned*)(hb + (size_t)(unsigned)(p & 0xffffffffu) * 32 + c4 * 4);
        float nm = __uint_as_float((unsigned)(p >> 32));
        acc.x = fmaf(nm, e4m3f(v & 255), acc.x);
        acc.y = fmaf(nm, e4m3f((v >> 8) & 255), acc.y);
        acc.z = fmaf(nm, e4m3f((v >> 16) & 255), acc.z);
        acc.w = fmaf(nm, e4m3f(v >> 24), acc.w);
    }
    int cb = c4 * 4;
    if (MODE == 0) {
        int ln = tid >> 3;
        srow[ln * 33 + cb + 0] = fmaxf(acc.x + bias[cb + 0], 0.0f);
        srow[ln * 33 + cb + 1] = fmaxf(acc.y + bias[cb + 1], 0.0f);
        srow[ln * 33 + cb + 2] = fmaxf(acc.z + bias[cb + 2], 0.0f);
        srow[ln * 33 + cb + 3] = fmaxf(acc.w + bias[cb + 3], 0.0f);
        __syncthreads();
        const float* rw = srow + ln * 33;
        float o0 = 0.f, o1 = 0.f, o2 = 0.f, o3 = 0.f;
#pragma unroll
        for (int kk = 0; kk < 32; ++kk) {
            float r = rw[kk];
            const float* wr = sW + kk * 32 + cb;
            o0 = fmaf(r, wr[0], o0);
            o1 = fmaf(r, wr[1], o1);
            o2 = fmaf(r, wr[2], o2);
            o3 = fmaf(r, wr[3], o3);
        }
        unsigned pk = f2e4m3(o0) | (f2e4m3(o1) << 8) | (f2e4m3(o2) << 16) | (f2e4m3(o3) << 24);
        *(unsigned*)(hout + (size_t)n * 32 + cb) = pk;
    } else {
        ushort4 ou;
        ou.x = f2bf(fmaxf(acc.x + bias[cb + 0], 0.0f));
        ou.y = f2bf(fmaxf(acc.y + bias[cb + 1], 0.0f));
        ou.z = f2bf(fmaxf(acc.z + bias[cb + 2], 0.0f));
        ou.w = f2bf(fmaxf(acc.w + bias[cb + 3], 0.0f));
        *((ushort4*)(h3out + (size_t)n * 32) + c4) = ou;
    }
}

// ---------- global mean pool (bf16 in, already relu+bias) + head + log_softmax ----------
__global__ __launch_bounds__(1024) void k_pool_head(const unsigned short* __restrict__ h3,
                                                    const int* __restrict__ batch,
                                                    const float* __restrict__ Wout,
                                                    const float* __restrict__ bout,
                                                    float* __restrict__ out) {
    int g = blockIdx.x;
    __shared__ int sb[2];
    if (threadIdx.x == 0) {
        int lo = 0, hi = NN;
        while (lo < hi) { int m = (lo + hi) >> 1; if (batch[m] < g) lo = m + 1; else hi = m; }
        sb[0] = lo;
        lo = 0; hi = NN;
        while (lo < hi) { int m = (lo + hi) >> 1; if (batch[m] < g + 1) lo = m + 1; else hi = m; }
        sb[1] = lo;
    }
    __syncthreads();
    int start = sb[0], end = sb[1];
    int c = threadIdx.x & 31, grp = threadIdx.x >> 5;
    float acc = 0.0f;
    for (int n = start + grp; n < end; n += 32)
        acc += bf2f(h3[(size_t)n * 32 + c]);
    __shared__ float red[32 * 32];
    red[grp * 32 + c] = acc;
    __syncthreads();
    __shared__ float pooled[32];
    if (threadIdx.x < 32) {
        float s = 0.0f;
#pragma unroll
        for (int gr = 0; gr < 32; ++gr) s += red[gr * 32 + threadIdx.x];
        pooled[threadIdx.x] = s / fmaxf((float)(end - start), 1.0f);
    }
    __syncthreads();
    __shared__ float slog[8];
    if (threadIdx.x < 8) {
        float l = bout[threadIdx.x];
#pragma unroll
        for (int k = 0; k < 32; ++k) l = fmaf(pooled[k], Wout[k * 8 + threadIdx.x], l);
        slog[threadIdx.x] = l;
    }
    __syncthreads();
    if (threadIdx.x < 8) {
        float m = slog[0];
#pragma unroll
        for (int i = 1; i < 8; ++i) m = fmaxf(m, slog[i]);
        float s = 0.0f;
#pragma unroll
        for (int i = 0; i < 8; ++i) s += expf(slog[i] - m);
        out[g * NC + threadIdx.x] = slog[threadIdx.x] - m - logf(s);
    }
}

extern "C" void kernel_launch(void* const* d_in, const int* in_sizes, int n_in,
                              void* d_out, int out_size, void* d_ws, size_t ws_size,
                              hipStream_t stream) {
    const float* x     = (const float*)d_in[0];
    const int*   eidx  = (const int*)d_in[1];
    const float* ew    = (const float*)d_in[2];
    const int*   batch = (const int*)d_in[3];
    const float* W1 = (const float*)d_in[4];
    const float* b1 = (const float*)d_in[5];
    const float* W2 = (const float*)d_in[6];
    const float* b2 = (const float*)d_in[7];
    const float* W3 = (const float*)d_in[8];
    const float* b3 = (const float*)d_in[9];
    const float* Wout = (const float*)d_in[10];
    const float* bout = (const float*)d_in[11];
    float* out = (float*)d_out;

    const int* row = eidx;        // sources
    const int* col = eidx + NE;   // targets

    // layout: h1 fp8 | h2 fp8 | h3 bf16 | pairs | staging | dinv | off | cntg | pcnt  (~41 MB)
    unsigned char* h1 = (unsigned char*)d_ws;                    // 3.2 MB
    unsigned char* h2 = h1 + (size_t)NN * HD;                    // 3.2 MB
    unsigned short* h3 = (unsigned short*)(h2 + (size_t)NN * HD);// 6.4 MB
    float2* pairs = (float2*)(h3 + (size_t)NN * HD);             // 12.8 MB
    uint2* staging = (uint2*)(pairs + NE);                       // 14.3 MB
    float* dinv = (float*)(staging + (size_t)P * SCAP);          // 0.4 MB
    int* off  = (int*)(dinv + NN);                               // 0.4 MB
    int* cntg = off + NN;                                        // 0.4 MB
    int* pcnt = cntg + NN;                                       // 1 KB

    hipMemsetAsync(pcnt, 0, P * sizeof(int), stream);
    k_bin<<<NBIN, 1024, 0, stream>>>(row, col, ew, pcnt, staging);
    k_csrA_gemm0<<<P + GEMM0_BLOCKS, 256, 0, stream>>>(pcnt, staging, off, cntg, dinv,
                                                       x, W1, h1);
    k_csr_b<<<P, 512, 0, stream>>>(pcnt, staging, off, dinv, pairs);
    k_gather<0><<<NORM_BLOCKS, 256, 0, stream>>>(h1, off, cntg, dinv, pairs, b1, W2,
                                                 h2, nullptr);
    k_gather<0><<<NORM_BLOCKS, 256, 0, stream>>>(h2, off, cntg, dinv, pairs, b2, W3,
                                                 h1, nullptr);
    k_gather<1><<<NORM_BLOCKS, 256, 0, stream>>>(h1, off, cntg, dinv, pairs, b3, nullptr,
                                                 nullptr, h3);
    k_pool_head<<<NG, 1024, 0, stream>>>(h3, batch, Wout, bout, out);
}

// Round 13
// 165.356 us; speedup vs baseline: 1.7359x; 1.5916x over previous
//
#include <hip/hip_runtime.h>
#include <math.h>

#define NN 100000
#define NE 1600000
#define HD 32
#define NG 64
#define NC 8

#define P 256        // partitions
#define PART 391     // nodes per partition; 391*256 = 100096 >= NN
#define SCAP 7000    // staging capacity per partition (Poisson(6250), +9 sigma)
#define CH 4096      // edges per k_bin block
#define NBIN ((NE + CH - 1) / CH)    // 391
#define NORM_BLOCKS (NN * 8 / 256)   // 3125 (gather grid)
#define GEMM0_BLOCKS (NN / 8)        // 12500

__device__ __forceinline__ float bf2f(unsigned short u) {
    return __uint_as_float(((unsigned int)u) << 16);
}
__device__ __forceinline__ unsigned short f2bf(float f) {
    unsigned int b = __float_as_uint(f);
    b = (b + 0x7FFFu + ((b >> 16) & 1u)) >> 16;  // RNE
    return (unsigned short)b;
}

// ---- fp8 helpers: hardware cvt if available, manual e4m3 fallback ----
#if __has_builtin(__builtin_amdgcn_cvt_pk_f32_fp8) && __has_builtin(__builtin_amdgcn_cvt_pk_fp8_f32)
#define FP8_HW 1
#else
#define FP8_HW 0
#endif

__device__ __forceinline__ float e4m3f_sw(unsigned u) {
    unsigned code = u & 0x7fu;
    unsigned e = code >> 3;
    float v;
    if (e == 0) v = (float)code * 0.001953125f;
    else v = __uint_as_float(((e + 120u) << 23) | ((code & 7u) << 20));
    return (u & 0x80u) ? -v : v;
}
__device__ __forceinline__ unsigned f2e4m3_sw(float f) {
    unsigned s = (__float_as_uint(f) >> 31) << 7;
    float a = fminf(fabsf(f), 448.0f);
    unsigned code;
    if (a >= 0.015625f) {
        unsigned x = __float_as_uint(a);
        x += 0x0007FFFFu + ((x >> 20) & 1u);
        code = (((x >> 23) - 120u) << 3) | ((x >> 20) & 7u);
    } else {
        code = (unsigned)__float2int_rn(a * 512.0f);
    }
    return s | code;
}

// decode 4 packed fp8 -> float4
__device__ __forceinline__ float4 fp8x4f(unsigned v) {
#if FP8_HW
    using floatx2 = __attribute__((ext_vector_type(2))) float;
    floatx2 lo = __builtin_amdgcn_cvt_pk_f32_fp8((int)v, false);
    floatx2 hi = __builtin_amdgcn_cvt_pk_f32_fp8((int)v, true);
    return make_float4(lo[0], lo[1], hi[0], hi[1]);
#else
    return make_float4(e4m3f_sw(v & 255), e4m3f_sw((v >> 8) & 255),
                       e4m3f_sw((v >> 16) & 255), e4m3f_sw(v >> 24));
#endif
}
// encode float4 -> 4 packed fp8
__device__ __forceinline__ unsigned f4fp8(float a, float b, float c, float d) {
#if FP8_HW
    int pk = 0;
    pk = __builtin_amdgcn_cvt_pk_fp8_f32(a, b, pk, false);
    pk = __builtin_amdgcn_cvt_pk_fp8_f32(c, d, pk, true);
    return (unsigned)pk;
#else
    return f2e4m3_sw(a) | (f2e4m3_sw(b) << 8) | (f2e4m3_sw(c) << 16) | (f2e4m3_sw(d) << 24);
#endif
}
// encode single float -> fp8 byte
__device__ __forceinline__ unsigned char f1fp8(float a) {
#if FP8_HW
    return (unsigned char)(__builtin_amdgcn_cvt_pk_fp8_f32(a, a, 0, false) & 0xff);
#else
    return (unsigned char)f2e4m3_sw(a);
#endif
}

// ---------- phase 1: bin edges into col-range partitions (1024 threads) ----------
// staging entry: x = col_lo | (row << 9), y = w bits
__global__ __launch_bounds__(1024) void k_bin(const int* __restrict__ row,
                                              const int* __restrict__ col,
                                              const float* __restrict__ w,
                                              int* __restrict__ pcnt,
                                              uint2* __restrict__ staging) {
    __shared__ int scol[CH];   // 16 KB
    __shared__ int hist[P];
    __shared__ int base_[P];
    int tid = threadIdx.x;
    int e0 = blockIdx.x * CH;
    int nrem = min(CH, NE - e0);
    if (tid < P) hist[tid] = 0;
    __syncthreads();
    for (int i = tid; i < nrem; i += 1024) {
        int c = col[e0 + i];
        scol[i] = c;
        atomicAdd(&hist[(unsigned)c / PART], 1);
    }
    __syncthreads();
    if (tid < P) {
        int h = hist[tid];
        base_[tid] = h ? atomicAdd(&pcnt[tid], h) : 0;
        hist[tid] = 0;
    }
    __syncthreads();
    for (int i = tid; i < nrem; i += 1024) {
        int c = scol[i];
        int p = (unsigned)c / PART;
        int pos = base_[p] + atomicAdd(&hist[p], 1);
        uint2 v;
        v.x = (unsigned)(c - p * PART) | ((unsigned)row[e0 + i] << 9);
        v.y = __float_as_uint(w[e0 + i]);
        staging[(size_t)p * SCAP + pos] = v;
    }
}

// ---------- phase 2a (fused with gemm0): counts + dinv + CSR offsets || h1 = fp8(x@W1) ----------
__global__ __launch_bounds__(256) void k_csrA_gemm0(const int* __restrict__ pcnt,
                                                    const uint2* __restrict__ staging,
                                                    int* __restrict__ off,
                                                    int* __restrict__ cntg,
                                                    float* __restrict__ dinv,
                                                    const float* __restrict__ x,
                                                    const float* __restrict__ W1,
                                                    unsigned char* __restrict__ h1) {
    int tid = threadIdx.x;
    if (blockIdx.x < P) {
        __shared__ int spc[P];
        __shared__ int cnt_l[PART];
        __shared__ float wsum[PART];
        __shared__ int sc[PART];
        int p = blockIdx.x;
        spc[tid] = pcnt[tid];
        __syncthreads();
#pragma unroll
        for (int d = 1; d < P; d <<= 1) {
            int t = (tid >= d) ? spc[tid - d] : 0;
            __syncthreads();
            spc[tid] += t;
            __syncthreads();
        }
        int m = pcnt[p];
        int pb = (p > 0) ? spc[p - 1] : 0;
        for (int i = tid; i < PART; i += 256) { cnt_l[i] = 0; wsum[i] = 0.0f; }
        __syncthreads();
        const uint2* st = staging + (size_t)p * SCAP;
        for (int i = tid; i < m; i += 256) {
            uint2 v = st[i];
            int cl = v.x & 511;
            atomicAdd(&cnt_l[cl], 1);
            atomicAdd(&wsum[cl], __uint_as_float(v.y));
        }
        __syncthreads();
        for (int i = tid; i < PART; i += 256) sc[i] = cnt_l[i];
        __syncthreads();
        int i0 = tid, i1 = tid + 256;
#pragma unroll
        for (int d = 1; d < 512; d <<= 1) {
            int t0 = 0, t1 = 0;
            if (i0 < PART && i0 >= d) t0 = sc[i0 - d];
            if (i1 < PART && i1 >= d) t1 = sc[i1 - d];
            __syncthreads();
            if (i0 < PART) sc[i0] += t0;
            if (i1 < PART) sc[i1] += t1;
            __syncthreads();
        }
        for (int i = tid; i < PART; i += 256) {
            int n = p * PART + i;
            if (n < NN) {
                off[n] = pb + sc[i] - cnt_l[i];
                cntg[n] = cnt_l[i];
                dinv[n] = rsqrtf(1.0f + wsum[i]);
            }
        }
    } else {
        __shared__ float sW[32 * 32];
        __shared__ float sX[8 * 32];
        int base = (blockIdx.x - P) * 8;
        ((float4*)sW)[tid] = ((const float4*)W1)[tid];
        if (tid < 64) ((float4*)sX)[tid] = ((const float4*)(x + (size_t)base * 32))[tid];
        __syncthreads();
        int c = tid & 31, nl = tid >> 5;
        float acc = 0.0f;
#pragma unroll
        for (int k = 0; k < 32; ++k) acc = fmaf(sX[nl * 32 + k], sW[k * 32 + c], acc);
        h1[(size_t)(base + nl) * 32 + c] = f1fp8(acc);
    }
}

// ---------- phase 2b: write final normalized pairs ----------
__global__ __launch_bounds__(512) void k_csr_b(const int* __restrict__ pcnt,
                                               const uint2* __restrict__ staging,
                                               const int* __restrict__ off,
                                               const float* __restrict__ dinv,
                                               float2* __restrict__ pairs) {
    __shared__ int cur[PART];
    __shared__ float sdc[PART];
    int p = blockIdx.x, tid = threadIdx.x;
    int m = pcnt[p];
    const uint2* st = staging + (size_t)p * SCAP;
    for (int i = tid; i < PART; i += 512) {
        int n = p * PART + i;
        cur[i] = (n < NN) ? off[n] : 0;
        sdc[i] = (n < NN) ? dinv[n] : 0.0f;
    }
    __syncthreads();
    for (int ib = tid; ib < m; ib += 512 * 4) {
        uint2 v[4];
        float dr[4];
#pragma unroll
        for (int j = 0; j < 4; ++j) {
            int i = ib + j * 512;
            if (i < m) v[j] = st[i];
        }
#pragma unroll
        for (int j = 0; j < 4; ++j) {
            int i = ib + j * 512;
            if (i < m) dr[j] = dinv[v[j].x >> 9];
        }
#pragma unroll
        for (int j = 0; j < 4; ++j) {
            int i = ib + j * 512;
            if (i < m) {
                int cl = v[j].x & 511;
                int pos = atomicAdd(&cur[cl], 1);
                float y = dr[j] * __uint_as_float(v[j].y) * sdc[cl];
                pairs[pos] = make_float2(__int_as_float((int)(v[j].x >> 9)), y);
            }
        }
    }
}

// ---------- gather (fp8 h): MODE 0 = fuse next GEMM (fp8 out), MODE 1 = bf16 relu out ----------
template <int MODE>
__global__ __launch_bounds__(256) void k_gather(const unsigned char* __restrict__ hb,
                                                const int* __restrict__ off,
                                                const int* __restrict__ cntg,
                                                const float* __restrict__ dinv,
                                                const float2* __restrict__ pairs,
                                                const float* __restrict__ bias,
                                                const float* __restrict__ Wn,
                                                unsigned char* __restrict__ hout,
                                                unsigned short* __restrict__ h3out) {
    __shared__ float sW[32 * 32];
    __shared__ float srow[32 * 33];
    int tid = threadIdx.x;
    if (MODE == 0) ((float4*)sW)[tid] = ((const float4*)Wn)[tid];
    int t = blockIdx.x * 256 + tid;  // NN*8 exact
    int n = t >> 3, c4 = t & 7;
    int cn = cntg[n];
    const unsigned long long* pp = (const unsigned long long*)(pairs + off[n]);
    float di = dinv[n], sl = di * di;
    unsigned hu = *(const unsigned*)(hb + (size_t)n * 32 + c4 * 4);
    float4 hf = fp8x4f(hu);
    float4 acc = make_float4(sl * hf.x, sl * hf.y, sl * hf.z, sl * hf.w);
    int k = 0;
    for (; k + 8 <= cn; k += 8) {
        unsigned long long p[8];
#pragma unroll
        for (int j = 0; j < 8; ++j) p[j] = __builtin_nontemporal_load(pp + k + j);
        unsigned v[8];
#pragma unroll
        for (int j = 0; j < 8; ++j)
            v[j] = *(const unsigned*)(hb + (size_t)(unsigned)(p[j] & 0xffffffffu) * 32 + c4 * 4);
#pragma unroll
        for (int j = 0; j < 8; ++j) {
            float nm = __uint_as_float((unsigned)(p[j] >> 32));
            float4 f = fp8x4f(v[j]);
            acc.x = fmaf(nm, f.x, acc.x);
            acc.y = fmaf(nm, f.y, acc.y);
            acc.z = fmaf(nm, f.z, acc.z);
            acc.w = fmaf(nm, f.w, acc.w);
        }
    }
    for (; k + 4 <= cn; k += 4) {
        unsigned long long p[4];
#pragma unroll
        for (int j = 0; j < 4; ++j) p[j] = __builtin_nontemporal_load(pp + k + j);
        unsigned v[4];
#pragma unroll
        for (int j = 0; j < 4; ++j)
            v[j] = *(const unsigned*)(hb + (size_t)(unsigned)(p[j] & 0xffffffffu) * 32 + c4 * 4);
#pragma unroll
        for (int j = 0; j < 4; ++j) {
            float nm = __uint_as_float((unsigned)(p[j] >> 32));
            float4 f = fp8x4f(v[j]);
            acc.x = fmaf(nm, f.x, acc.x);
            acc.y = fmaf(nm, f.y, acc.y);
            acc.z = fmaf(nm, f.z, acc.z);
            acc.w = fmaf(nm, f.w, acc.w);
        }
    }
    for (; k < cn; ++k) {
        unsigned long long p = __builtin_nontemporal_load(pp + k);
        unsigned v = *(const unsigned*)(hb + (size_t)(unsigned)(p & 0xffffffffu) * 32 + c4 * 4);
        float nm = __uint_as_float((unsigned)(p >> 32));
        float4 f = fp8x4f(v);
        acc.x = fmaf(nm, f.x, acc.x);
        acc.y = fmaf(nm, f.y, acc.y);
        acc.z = fmaf(nm, f.z, acc.z);
        acc.w = fmaf(nm, f.w, acc.w);
    }
    int cb = c4 * 4;
    if (MODE == 0) {
        int ln = tid >> 3;
        srow[ln * 33 + cb + 0] = fmaxf(acc.x + bias[cb + 0], 0.0f);
        srow[ln * 33 + cb + 1] = fmaxf(acc.y + bias[cb + 1], 0.0f);
        srow[ln * 33 + cb + 2] = fmaxf(acc.z + bias[cb + 2], 0.0f);
        srow[ln * 33 + cb + 3] = fmaxf(acc.w + bias[cb + 3], 0.0f);
        __syncthreads();
        const float* rw = srow + ln * 33;
        float o0 = 0.f, o1 = 0.f, o2 = 0.f, o3 = 0.f;
#pragma unroll
        for (int kk = 0; kk < 32; ++kk) {
            float r = rw[kk];
            const float* wr = sW + kk * 32 + cb;
            o0 = fmaf(r, wr[0], o0);
            o1 = fmaf(r, wr[1], o1);
            o2 = fmaf(r, wr[2], o2);
            o3 = fmaf(r, wr[3], o3);
        }
        *(unsigned*)(hout + (size_t)n * 32 + cb) = f4fp8(o0, o1, o2, o3);
    } else {
        ushort4 ou;
        ou.x = f2bf(fmaxf(acc.x + bias[cb + 0], 0.0f));
        ou.y = f2bf(fmaxf(acc.y + bias[cb + 1], 0.0f));
        ou.z = f2bf(fmaxf(acc.z + bias[cb + 2], 0.0f));
        ou.w = f2bf(fmaxf(acc.w + bias[cb + 3], 0.0f));
        *((ushort4*)(h3out + (size_t)n * 32) + c4) = ou;
    }
}

// ---------- global mean pool (bf16 in, already relu+bias) + head + log_softmax ----------
__global__ __launch_bounds__(1024) void k_pool_head(const unsigned short* __restrict__ h3,
                                                    const int* __restrict__ batch,
                                                    const float* __restrict__ Wout,
                                                    const float* __restrict__ bout,
                                                    float* __restrict__ out) {
    int g = blockIdx.x;
    __shared__ int sb[2];
    if (threadIdx.x == 0) {
        int lo = 0, hi = NN;
        while (lo < hi) { int m = (lo + hi) >> 1; if (batch[m] < g) lo = m + 1; else hi = m; }
        sb[0] = lo;
        lo = 0; hi = NN;
        while (lo < hi) { int m = (lo + hi) >> 1; if (batch[m] < g + 1) lo = m + 1; else hi = m; }
        sb[1] = lo;
    }
    __syncthreads();
    int start = sb[0], end = sb[1];
    int c = threadIdx.x & 31, grp = threadIdx.x >> 5;
    float acc = 0.0f;
    for (int n = start + grp; n < end; n += 32)
        acc += bf2f(h3[(size_t)n * 32 + c]);
    __shared__ float red[32 * 32];
    red[grp * 32 + c] = acc;
    __syncthreads();
    __shared__ float pooled[32];
    if (threadIdx.x < 32) {
        float s = 0.0f;
#pragma unroll
        for (int gr = 0; gr < 32; ++gr) s += red[gr * 32 + threadIdx.x];
        pooled[threadIdx.x] = s / fmaxf((float)(end - start), 1.0f);
    }
    __syncthreads();
    __shared__ float slog[8];
    if (threadIdx.x < 8) {
        float l = bout[threadIdx.x];
#pragma unroll
        for (int k = 0; k < 32; ++k) l = fmaf(pooled[k], Wout[k * 8 + threadIdx.x], l);
        slog[threadIdx.x] = l;
    }
    __syncthreads();
    if (threadIdx.x < 8) {
        float m = slog[0];
#pragma unroll
        for (int i = 1; i < 8; ++i) m = fmaxf(m, slog[i]);
        float s = 0.0f;
#pragma unroll
        for (int i = 0; i < 8; ++i) s += expf(slog[i] - m);
        out[g * NC + threadIdx.x] = slog[threadIdx.x] - m - logf(s);
    }
}

extern "C" void kernel_launch(void* const* d_in, const int* in_sizes, int n_in,
                              void* d_out, int out_size, void* d_ws, size_t ws_size,
                              hipStream_t stream) {
    const float* x     = (const float*)d_in[0];
    const int*   eidx  = (const int*)d_in[1];
    const float* ew    = (const float*)d_in[2];
    const int*   batch = (const int*)d_in[3];
    const float* W1 = (const float*)d_in[4];
    const float* b1 = (const float*)d_in[5];
    const float* W2 = (const float*)d_in[6];
    const float* b2 = (const float*)d_in[7];
    const float* W3 = (const float*)d_in[8];
    const float* b3 = (const float*)d_in[9];
    const float* Wout = (const float*)d_in[10];
    const float* bout = (const float*)d_in[11];
    float* out = (float*)d_out;

    const int* row = eidx;        // sources
    const int* col = eidx + NE;   // targets

    // layout: h1 fp8 | h2 fp8 | h3 bf16 | pairs | staging | dinv | off | cntg | pcnt  (~41 MB)
    unsigned char* h1 = (unsigned char*)d_ws;                    // 3.2 MB
    unsigned char* h2 = h1 + (size_t)NN * HD;                    // 3.2 MB
    unsigned short* h3 = (unsigned short*)(h2 + (size_t)NN * HD);// 6.4 MB
    float2* pairs = (float2*)(h3 + (size_t)NN * HD);             // 12.8 MB
    uint2* staging = (uint2*)(pairs + NE);                       // 14.3 MB
    float* dinv = (float*)(staging + (size_t)P * SCAP);          // 0.4 MB
    int* off  = (int*)(dinv + NN);                               // 0.4 MB
    int* cntg = off + NN;                                        // 0.4 MB
    int* pcnt = cntg + NN;                                       // 1 KB

    hipMemsetAsync(pcnt, 0, P * sizeof(int), stream);
    k_bin<<<NBIN, 1024, 0, stream>>>(row, col, ew, pcnt, staging);
    k_csrA_gemm0<<<P + GEMM0_BLOCKS, 256, 0, stream>>>(pcnt, staging, off, cntg, dinv,
                                                       x, W1, h1);
    k_csr_b<<<P, 512, 0, stream>>>(pcnt, staging, off, dinv, pairs);
    k_gather<0><<<NORM_BLOCKS, 256, 0, stream>>>(h1, off, cntg, dinv, pairs, b1, W2,
                                                 h2, nullptr);
    k_gather<0><<<NORM_BLOCKS, 256, 0, stream>>>(h2, off, cntg, dinv, pairs, b2, W3,
                                                 h1, nullptr);
    k_gather<1><<<NORM_BLOCKS, 256, 0, stream>>>(h1, off, cntg, dinv, pairs, b3, nullptr,
                                                 nullptr, h3);
    k_pool_head<<<NG, 1024, 0, stream>>>(h3, batch, Wout, bout, out);
}

// Round 14
// 154.752 us; speedup vs baseline: 1.8549x; 1.0685x over previous
//
#include <hip/hip_runtime.h>
#include <math.h>

#define NN 100000
#define NE 1600000
#define HD 32
#define NG 64
#define NC 8

#define P 256        // partitions
#define PART 391     // nodes per partition; 391*256 = 100096 >= NN
#define SCAP 7000    // staging capacity per partition (Poisson(6250), +9 sigma)
#define CH 4096      // edges per k_bin block
#define NBIN ((NE + CH - 1) / CH)    // 391
#define NORM_BLOCKS (NN * 8 / 256)   // 3125 (gather grid)
#define GEMM0_BLOCKS (NN / 8)        // 12500

__device__ __forceinline__ float bf2f(unsigned short u) {
    return __uint_as_float(((unsigned int)u) << 16);
}
__device__ __forceinline__ unsigned short f2bf(float f) {
    unsigned int b = __float_as_uint(f);
    b = (b + 0x7FFFu + ((b >> 16) & 1u)) >> 16;  // RNE
    return (unsigned short)b;
}

// ---- fp8 helpers: hardware cvt if available, manual e4m3 fallback ----
#if __has_builtin(__builtin_amdgcn_cvt_pk_f32_fp8) && __has_builtin(__builtin_amdgcn_cvt_pk_fp8_f32)
#define FP8_HW 1
#else
#define FP8_HW 0
#endif

__device__ __forceinline__ float e4m3f_sw(unsigned u) {
    unsigned code = u & 0x7fu;
    unsigned e = code >> 3;
    float v;
    if (e == 0) v = (float)code * 0.001953125f;
    else v = __uint_as_float(((e + 120u) << 23) | ((code & 7u) << 20));
    return (u & 0x80u) ? -v : v;
}
__device__ __forceinline__ unsigned f2e4m3_sw(float f) {
    unsigned s = (__float_as_uint(f) >> 31) << 7;
    float a = fminf(fabsf(f), 448.0f);
    unsigned code;
    if (a >= 0.015625f) {
        unsigned x = __float_as_uint(a);
        x += 0x0007FFFFu + ((x >> 20) & 1u);
        code = (((x >> 23) - 120u) << 3) | ((x >> 20) & 7u);
    } else {
        code = (unsigned)__float2int_rn(a * 512.0f);
    }
    return s | code;
}

// decode 4 packed fp8 -> float4
__device__ __forceinline__ float4 fp8x4f(unsigned v) {
#if FP8_HW
    using floatx2 = __attribute__((ext_vector_type(2))) float;
    floatx2 lo = __builtin_amdgcn_cvt_pk_f32_fp8((int)v, false);
    floatx2 hi = __builtin_amdgcn_cvt_pk_f32_fp8((int)v, true);
    return make_float4(lo[0], lo[1], hi[0], hi[1]);
#else
    return make_float4(e4m3f_sw(v & 255), e4m3f_sw((v >> 8) & 255),
                       e4m3f_sw((v >> 16) & 255), e4m3f_sw(v >> 24));
#endif
}
// encode float4 -> 4 packed fp8
__device__ __forceinline__ unsigned f4fp8(float a, float b, float c, float d) {
#if FP8_HW
    int pk = 0;
    pk = __builtin_amdgcn_cvt_pk_fp8_f32(a, b, pk, false);
    pk = __builtin_amdgcn_cvt_pk_fp8_f32(c, d, pk, true);
    return (unsigned)pk;
#else
    return f2e4m3_sw(a) | (f2e4m3_sw(b) << 8) | (f2e4m3_sw(c) << 16) | (f2e4m3_sw(d) << 24);
#endif
}
// encode single float -> fp8 byte
__device__ __forceinline__ unsigned char f1fp8(float a) {
#if FP8_HW
    return (unsigned char)(__builtin_amdgcn_cvt_pk_fp8_f32(a, a, 0, false) & 0xff);
#else
    return (unsigned char)f2e4m3_sw(a);
#endif
}

// ---------- phase 1: bin edges into col-range partitions (1024 threads) ----------
// staging entry: x = col_lo | (row << 9), y = w bits
__global__ __launch_bounds__(1024) void k_bin(const int* __restrict__ row,
                                              const int* __restrict__ col,
                                              const float* __restrict__ w,
                                              int* __restrict__ pcnt,
                                              uint2* __restrict__ staging) {
    __shared__ int scol[CH];   // 16 KB
    __shared__ int hist[P];
    __shared__ int base_[P];
    int tid = threadIdx.x;
    int e0 = blockIdx.x * CH;
    int nrem = min(CH, NE - e0);
    if (tid < P) hist[tid] = 0;
    __syncthreads();
    for (int i = tid; i < nrem; i += 1024) {
        int c = col[e0 + i];
        scol[i] = c;
        atomicAdd(&hist[(unsigned)c / PART], 1);
    }
    __syncthreads();
    if (tid < P) {
        int h = hist[tid];
        base_[tid] = h ? atomicAdd(&pcnt[tid], h) : 0;
        hist[tid] = 0;
    }
    __syncthreads();
    for (int i = tid; i < nrem; i += 1024) {
        int c = scol[i];
        int p = (unsigned)c / PART;
        int pos = base_[p] + atomicAdd(&hist[p], 1);
        uint2 v;
        v.x = (unsigned)(c - p * PART) | ((unsigned)row[e0 + i] << 9);
        v.y = __float_as_uint(w[e0 + i]);
        staging[(size_t)p * SCAP + pos] = v;
    }
}

// ---------- phase 2a (fused with gemm0): counts + dinv + CSR offsets || h1 = fp8(x@W1) ----------
__global__ __launch_bounds__(256) void k_csrA_gemm0(const int* __restrict__ pcnt,
                                                    const uint2* __restrict__ staging,
                                                    int* __restrict__ off,
                                                    int* __restrict__ cntg,
                                                    float* __restrict__ dinv,
                                                    const float* __restrict__ x,
                                                    const float* __restrict__ W1,
                                                    unsigned char* __restrict__ h1) {
    int tid = threadIdx.x;
    if (blockIdx.x < P) {
        __shared__ int spc[P];
        __shared__ int cnt_l[PART];
        __shared__ float wsum[PART];
        __shared__ int sc[PART];
        int p = blockIdx.x;
        spc[tid] = pcnt[tid];
        __syncthreads();
#pragma unroll
        for (int d = 1; d < P; d <<= 1) {
            int t = (tid >= d) ? spc[tid - d] : 0;
            __syncthreads();
            spc[tid] += t;
            __syncthreads();
        }
        int m = pcnt[p];
        int pb = (p > 0) ? spc[p - 1] : 0;
        for (int i = tid; i < PART; i += 256) { cnt_l[i] = 0; wsum[i] = 0.0f; }
        __syncthreads();
        const uint2* st = staging + (size_t)p * SCAP;
        for (int i = tid; i < m; i += 256) {
            uint2 v = st[i];
            int cl = v.x & 511;
            atomicAdd(&cnt_l[cl], 1);
            atomicAdd(&wsum[cl], __uint_as_float(v.y));
        }
        __syncthreads();
        for (int i = tid; i < PART; i += 256) sc[i] = cnt_l[i];
        __syncthreads();
        int i0 = tid, i1 = tid + 256;
#pragma unroll
        for (int d = 1; d < 512; d <<= 1) {
            int t0 = 0, t1 = 0;
            if (i0 < PART && i0 >= d) t0 = sc[i0 - d];
            if (i1 < PART && i1 >= d) t1 = sc[i1 - d];
            __syncthreads();
            if (i0 < PART) sc[i0] += t0;
            if (i1 < PART) sc[i1] += t1;
            __syncthreads();
        }
        for (int i = tid; i < PART; i += 256) {
            int n = p * PART + i;
            if (n < NN) {
                off[n] = pb + sc[i] - cnt_l[i];
                cntg[n] = cnt_l[i];
                dinv[n] = rsqrtf(1.0f + wsum[i]);
            }
        }
    } else {
        __shared__ float sW[32 * 32];
        __shared__ float sX[8 * 32];
        int base = (blockIdx.x - P) * 8;
        ((float4*)sW)[tid] = ((const float4*)W1)[tid];
        if (tid < 64) ((float4*)sX)[tid] = ((const float4*)(x + (size_t)base * 32))[tid];
        __syncthreads();
        int c = tid & 31, nl = tid >> 5;
        float acc = 0.0f;
#pragma unroll
        for (int k = 0; k < 32; ++k) acc = fmaf(sX[nl * 32 + k], sW[k * 32 + c], acc);
        h1[(size_t)(base + nl) * 32 + c] = f1fp8(acc);
    }
}

// ---------- phase 2b: write final normalized pairs, 4B packed (row<<15 | norm15) ----------
__global__ __launch_bounds__(512) void k_csr_b(const int* __restrict__ pcnt,
                                               const uint2* __restrict__ staging,
                                               const int* __restrict__ off,
                                               const float* __restrict__ dinv,
                                               unsigned* __restrict__ pairs) {
    __shared__ int cur[PART];
    __shared__ float sdc[PART];
    int p = blockIdx.x, tid = threadIdx.x;
    int m = pcnt[p];
    const uint2* st = staging + (size_t)p * SCAP;
    for (int i = tid; i < PART; i += 512) {
        int n = p * PART + i;
        cur[i] = (n < NN) ? off[n] : 0;
        sdc[i] = (n < NN) ? dinv[n] : 0.0f;
    }
    __syncthreads();
    for (int ib = tid; ib < m; ib += 512 * 4) {
        uint2 v[4];
        float dr[4];
#pragma unroll
        for (int j = 0; j < 4; ++j) {
            int i = ib + j * 512;
            if (i < m) v[j] = st[i];
        }
#pragma unroll
        for (int j = 0; j < 4; ++j) {
            int i = ib + j * 512;
            if (i < m) dr[j] = dinv[v[j].x >> 9];
        }
#pragma unroll
        for (int j = 0; j < 4; ++j) {
            int i = ib + j * 512;
            if (i < m) {
                int cl = v[j].x & 511;
                int pos = atomicAdd(&cur[cl], 1);
                float y = dr[j] * __uint_as_float(v[j].y) * sdc[cl];
                unsigned q = (unsigned)__float2int_rn(y * 32768.0f);
                q = min(q, 32767u);
                pairs[pos] = ((v[j].x >> 9) << 15) | q;
            }
        }
    }
}

// ---------- gather (fp8 h, 4B pairs): MODE 0 = fuse next GEMM, MODE 1 = bf16 relu out ----------
#define NM_SCALE 3.0517578125e-5f  // 1/32768
template <int MODE>
__global__ __launch_bounds__(256) void k_gather(const unsigned char* __restrict__ hb,
                                                const int* __restrict__ off,
                                                const int* __restrict__ cntg,
                                                const float* __restrict__ dinv,
                                                const unsigned* __restrict__ pairs,
                                                const float* __restrict__ bias,
                                                const float* __restrict__ Wn,
                                                unsigned char* __restrict__ hout,
                                                unsigned short* __restrict__ h3out) {
    __shared__ float sW[32 * 32];
    __shared__ float srow[32 * 33];
    int tid = threadIdx.x;
    if (MODE == 0) ((float4*)sW)[tid] = ((const float4*)Wn)[tid];
    int t = blockIdx.x * 256 + tid;  // NN*8 exact
    int n = t >> 3, c4 = t & 7;
    int cn = cntg[n];
    const unsigned* pp = pairs + off[n];
    float di = dinv[n], sl = di * di;
    unsigned hu = *(const unsigned*)(hb + (size_t)n * 32 + c4 * 4);
    float4 hf = fp8x4f(hu);
    float4 acc = make_float4(sl * hf.x, sl * hf.y, sl * hf.z, sl * hf.w);
    int k = 0;
    for (; k + 8 <= cn; k += 8) {
        unsigned p[8];
#pragma unroll
        for (int j = 0; j < 8; ++j) p[j] = __builtin_nontemporal_load(pp + k + j);
        unsigned v[8];
#pragma unroll
        for (int j = 0; j < 8; ++j)
            v[j] = *(const unsigned*)(hb + (size_t)(p[j] >> 15) * 32 + c4 * 4);
#pragma unroll
        for (int j = 0; j < 8; ++j) {
            float nm = (float)(p[j] & 32767u) * NM_SCALE;
            float4 f = fp8x4f(v[j]);
            acc.x = fmaf(nm, f.x, acc.x);
            acc.y = fmaf(nm, f.y, acc.y);
            acc.z = fmaf(nm, f.z, acc.z);
            acc.w = fmaf(nm, f.w, acc.w);
        }
    }
    for (; k + 4 <= cn; k += 4) {
        unsigned p[4];
#pragma unroll
        for (int j = 0; j < 4; ++j) p[j] = __builtin_nontemporal_load(pp + k + j);
        unsigned v[4];
#pragma unroll
        for (int j = 0; j < 4; ++j)
            v[j] = *(const unsigned*)(hb + (size_t)(p[j] >> 15) * 32 + c4 * 4);
#pragma unroll
        for (int j = 0; j < 4; ++j) {
            float nm = (float)(p[j] & 32767u) * NM_SCALE;
            float4 f = fp8x4f(v[j]);
            acc.x = fmaf(nm, f.x, acc.x);
            acc.y = fmaf(nm, f.y, acc.y);
            acc.z = fmaf(nm, f.z, acc.z);
            acc.w = fmaf(nm, f.w, acc.w);
        }
    }
    for (; k < cn; ++k) {
        unsigned p = __builtin_nontemporal_load(pp + k);
        unsigned v = *(const unsigned*)(hb + (size_t)(p >> 15) * 32 + c4 * 4);
        float nm = (float)(p & 32767u) * NM_SCALE;
        float4 f = fp8x4f(v);
        acc.x = fmaf(nm, f.x, acc.x);
        acc.y = fmaf(nm, f.y, acc.y);
        acc.z = fmaf(nm, f.z, acc.z);
        acc.w = fmaf(nm, f.w, acc.w);
    }
    int cb = c4 * 4;
    if (MODE == 0) {
        int ln = tid >> 3;
        srow[ln * 33 + cb + 0] = fmaxf(acc.x + bias[cb + 0], 0.0f);
        srow[ln * 33 + cb + 1] = fmaxf(acc.y + bias[cb + 1], 0.0f);
        srow[ln * 33 + cb + 2] = fmaxf(acc.z + bias[cb + 2], 0.0f);
        srow[ln * 33 + cb + 3] = fmaxf(acc.w + bias[cb + 3], 0.0f);
        __syncthreads();
        const float* rw = srow + ln * 33;
        float o0 = 0.f, o1 = 0.f, o2 = 0.f, o3 = 0.f;
#pragma unroll
        for (int kk = 0; kk < 32; ++kk) {
            float r = rw[kk];
            const float* wr = sW + kk * 32 + cb;
            o0 = fmaf(r, wr[0], o0);
            o1 = fmaf(r, wr[1], o1);
            o2 = fmaf(r, wr[2], o2);
            o3 = fmaf(r, wr[3], o3);
        }
        *(unsigned*)(hout + (size_t)n * 32 + cb) = f4fp8(o0, o1, o2, o3);
    } else {
        ushort4 ou;
        ou.x = f2bf(fmaxf(acc.x + bias[cb + 0], 0.0f));
        ou.y = f2bf(fmaxf(acc.y + bias[cb + 1], 0.0f));
        ou.z = f2bf(fmaxf(acc.z + bias[cb + 2], 0.0f));
        ou.w = f2bf(fmaxf(acc.w + bias[cb + 3], 0.0f));
        *((ushort4*)(h3out + (size_t)n * 32) + c4) = ou;
    }
}

// ---------- global mean pool (bf16 in, already relu+bias) + head + log_softmax ----------
__global__ __launch_bounds__(1024) void k_pool_head(const unsigned short* __restrict__ h3,
                                                    const int* __restrict__ batch,
                                                    const float* __restrict__ Wout,
                                                    const float* __restrict__ bout,
                                                    float* __restrict__ out) {
    int g = blockIdx.x;
    __shared__ int sb[2];
    if (threadIdx.x == 0) {
        int lo = 0, hi = NN;
        while (lo < hi) { int m = (lo + hi) >> 1; if (batch[m] < g) lo = m + 1; else hi = m; }
        sb[0] = lo;
        lo = 0; hi = NN;
        while (lo < hi) { int m = (lo + hi) >> 1; if (batch[m] < g + 1) lo = m + 1; else hi = m; }
        sb[1] = lo;
    }
    __syncthreads();
    int start = sb[0], end = sb[1];
    int c = threadIdx.x & 31, grp = threadIdx.x >> 5;
    float acc = 0.0f;
    for (int n = start + grp; n < end; n += 32)
        acc += bf2f(h3[(size_t)n * 32 + c]);
    __shared__ float red[32 * 32];
    red[grp * 32 + c] = acc;
    __syncthreads();
    __shared__ float pooled[32];
    if (threadIdx.x < 32) {
        float s = 0.0f;
#pragma unroll
        for (int gr = 0; gr < 32; ++gr) s += red[gr * 32 + threadIdx.x];
        pooled[threadIdx.x] = s / fmaxf((float)(end - start), 1.0f);
    }
    __syncthreads();
    __shared__ float slog[8];
    if (threadIdx.x < 8) {
        float l = bout[threadIdx.x];
#pragma unroll
        for (int k = 0; k < 32; ++k) l = fmaf(pooled[k], Wout[k * 8 + threadIdx.x], l);
        slog[threadIdx.x] = l;
    }
    __syncthreads();
    if (threadIdx.x < 8) {
        float m = slog[0];
#pragma unroll
        for (int i = 1; i < 8; ++i) m = fmaxf(m, slog[i]);
        float s = 0.0f;
#pragma unroll
        for (int i = 0; i < 8; ++i) s += expf(slog[i] - m);
        out[g * NC + threadIdx.x] = slog[threadIdx.x] - m - logf(s);
    }
}

extern "C" void kernel_launch(void* const* d_in, const int* in_sizes, int n_in,
                              void* d_out, int out_size, void* d_ws, size_t ws_size,
                              hipStream_t stream) {
    const float* x     = (const float*)d_in[0];
    const int*   eidx  = (const int*)d_in[1];
    const float* ew    = (const float*)d_in[2];
    const int*   batch = (const int*)d_in[3];
    const float* W1 = (const float*)d_in[4];
    const float* b1 = (const float*)d_in[5];
    const float* W2 = (const float*)d_in[6];
    const float* b2 = (const float*)d_in[7];
    const float* W3 = (const float*)d_in[8];
    const float* b3 = (const float*)d_in[9];
    const float* Wout = (const float*)d_in[10];
    const float* bout = (const float*)d_in[11];
    float* out = (float*)d_out;

    const int* row = eidx;        // sources
    const int* col = eidx + NE;   // targets

    // layout: h1 fp8 | h2 fp8 | h3 bf16 | pairs(4B) | staging | dinv | off | cntg | pcnt (~35 MB)
    unsigned char* h1 = (unsigned char*)d_ws;                    // 3.2 MB
    unsigned char* h2 = h1 + (size_t)NN * HD;                    // 3.2 MB
    unsigned short* h3 = (unsigned short*)(h2 + (size_t)NN * HD);// 6.4 MB
    unsigned* pairs = (unsigned*)(h3 + (size_t)NN * HD);         // 6.4 MB
    uint2* staging = (uint2*)(pairs + NE);                       // 14.3 MB
    float* dinv = (float*)(staging + (size_t)P * SCAP);          // 0.4 MB
    int* off  = (int*)(dinv + NN);                               // 0.4 MB
    int* cntg = off + NN;                                        // 0.4 MB
    int* pcnt = cntg + NN;                                       // 1 KB

    hipMemsetAsync(pcnt, 0, P * sizeof(int), stream);
    k_bin<<<NBIN, 1024, 0, stream>>>(row, col, ew, pcnt, staging);
    k_csrA_gemm0<<<P + GEMM0_BLOCKS, 256, 0, stream>>>(pcnt, staging, off, cntg, dinv,
                                                       x, W1, h1);
    k_csr_b<<<P, 512, 0, stream>>>(pcnt, staging, off, dinv, pairs);
    k_gather<0><<<NORM_BLOCKS, 256, 0, stream>>>(h1, off, cntg, dinv, pairs, b1, W2,
                                                 h2, nullptr);
    k_gather<0><<<NORM_BLOCKS, 256, 0, stream>>>(h2, off, cntg, dinv, pairs, b2, W3,
                                                 h1, nullptr);
    k_gather<1><<<NORM_BLOCKS, 256, 0, stream>>>(h1, off, cntg, dinv, pairs, b3, nullptr,
                                                 nullptr, h3);
    k_pool_head<<<NG, 1024, 0, stream>>>(h3, batch, Wout, bout, out);
}

// Round 15
// 134.186 us; speedup vs baseline: 2.1392x; 1.1533x over previous
//
#include <hip/hip_runtime.h>
#include <math.h>

#define NN 100000
#define NE 1600000
#define HD 32
#define NG 64
#define NC 8

#define P 256        // partitions
#define PART 391     // nodes per partition; 391*256 = 100096 >= NN
#define SCAP 7000    // staging capacity per partition (Poisson(6250), +9 sigma)
#define CH 8192      // edges per k_bin block
#define NBIN ((NE + CH - 1) / CH)    // 196
#define NORM_BLOCKS (NN * 8 / 256)   // 3125 (gather grid)
#define GEMM0_BLOCKS (NN / 8)        // 12500

__device__ __forceinline__ float bf2f(unsigned short u) {
    return __uint_as_float(((unsigned int)u) << 16);
}
__device__ __forceinline__ unsigned short f2bf(float f) {
    unsigned int b = __float_as_uint(f);
    b = (b + 0x7FFFu + ((b >> 16) & 1u)) >> 16;  // RNE
    return (unsigned short)b;
}

// ---- fp8 helpers: hardware cvt if available, manual e4m3 fallback ----
#if __has_builtin(__builtin_amdgcn_cvt_pk_f32_fp8) && __has_builtin(__builtin_amdgcn_cvt_pk_fp8_f32)
#define FP8_HW 1
#else
#define FP8_HW 0
#endif

__device__ __forceinline__ float e4m3f_sw(unsigned u) {
    unsigned code = u & 0x7fu;
    unsigned e = code >> 3;
    float v;
    if (e == 0) v = (float)code * 0.001953125f;
    else v = __uint_as_float(((e + 120u) << 23) | ((code & 7u) << 20));
    return (u & 0x80u) ? -v : v;
}
__device__ __forceinline__ unsigned f2e4m3_sw(float f) {
    unsigned s = (__float_as_uint(f) >> 31) << 7;
    float a = fminf(fabsf(f), 448.0f);
    unsigned code;
    if (a >= 0.015625f) {
        unsigned x = __float_as_uint(a);
        x += 0x0007FFFFu + ((x >> 20) & 1u);
        code = (((x >> 23) - 120u) << 3) | ((x >> 20) & 7u);
    } else {
        code = (unsigned)__float2int_rn(a * 512.0f);
    }
    return s | code;
}

// decode 4 packed fp8 -> float4
__device__ __forceinline__ float4 fp8x4f(unsigned v) {
#if FP8_HW
    using floatx2 = __attribute__((ext_vector_type(2))) float;
    floatx2 lo = __builtin_amdgcn_cvt_pk_f32_fp8((int)v, false);
    floatx2 hi = __builtin_amdgcn_cvt_pk_f32_fp8((int)v, true);
    return make_float4(lo[0], lo[1], hi[0], hi[1]);
#else
    return make_float4(e4m3f_sw(v & 255), e4m3f_sw((v >> 8) & 255),
                       e4m3f_sw((v >> 16) & 255), e4m3f_sw(v >> 24));
#endif
}
// encode float4 -> 4 packed fp8
__device__ __forceinline__ unsigned f4fp8(float a, float b, float c, float d) {
#if FP8_HW
    int pk = 0;
    pk = __builtin_amdgcn_cvt_pk_fp8_f32(a, b, pk, false);
    pk = __builtin_amdgcn_cvt_pk_fp8_f32(c, d, pk, true);
    return (unsigned)pk;
#else
    return f2e4m3_sw(a) | (f2e4m3_sw(b) << 8) | (f2e4m3_sw(c) << 16) | (f2e4m3_sw(d) << 24);
#endif
}
// encode single float -> fp8 byte
__device__ __forceinline__ unsigned char f1fp8(float a) {
#if FP8_HW
    return (unsigned char)(__builtin_amdgcn_cvt_pk_fp8_f32(a, a, 0, false) & 0xff);
#else
    return (unsigned char)f2e4m3_sw(a);
#endif
}

// ---------- phase 1: bin edges into col-range partitions (1024 threads) ----------
// staging entry: x = col_lo | (row << 9), y = w bits
__global__ __launch_bounds__(1024) void k_bin(const int* __restrict__ row,
                                              const int* __restrict__ col,
                                              const float* __restrict__ w,
                                              int* __restrict__ pcnt,
                                              uint2* __restrict__ staging) {
    __shared__ int scol[CH];   // 32 KB
    __shared__ int hist[P];
    __shared__ int base_[P];
    int tid = threadIdx.x;
    int e0 = blockIdx.x * CH;
    int nrem = min(CH, NE - e0);
    if (tid < P) hist[tid] = 0;
    __syncthreads();
    for (int i = tid; i < nrem; i += 1024) {
        int c = col[e0 + i];
        scol[i] = c;
        atomicAdd(&hist[(unsigned)c / PART], 1);
    }
    __syncthreads();
    if (tid < P) {
        int h = hist[tid];
        base_[tid] = h ? atomicAdd(&pcnt[tid], h) : 0;
        hist[tid] = 0;
    }
    __syncthreads();
    for (int i = tid; i < nrem; i += 1024) {
        int c = scol[i];
        int p = (unsigned)c / PART;
        int pos = base_[p] + atomicAdd(&hist[p], 1);
        uint2 v;
        v.x = (unsigned)(c - p * PART) | ((unsigned)row[e0 + i] << 9);
        v.y = __float_as_uint(w[e0 + i]);
        staging[(size_t)p * SCAP + pos] = v;
    }
}

// ---------- phase 2a (fused with gemm0): counts + dinv + CSR offsets || h1 = fp8(x@W1) ----------
__global__ __launch_bounds__(256) void k_csrA_gemm0(const int* __restrict__ pcnt,
                                                    const uint2* __restrict__ staging,
                                                    int* __restrict__ off,
                                                    int* __restrict__ cntg,
                                                    float* __restrict__ dinv,
                                                    const float* __restrict__ x,
                                                    const float* __restrict__ W1,
                                                    unsigned char* __restrict__ h1) {
    int tid = threadIdx.x;
    if (blockIdx.x < P) {
        __shared__ int spc[P];
        __shared__ int cnt_l[PART];
        __shared__ float wsum[PART];
        __shared__ int sc[PART];
        int p = blockIdx.x;
        spc[tid] = pcnt[tid];
        __syncthreads();
#pragma unroll
        for (int d = 1; d < P; d <<= 1) {
            int t = (tid >= d) ? spc[tid - d] : 0;
            __syncthreads();
            spc[tid] += t;
            __syncthreads();
        }
        int m = pcnt[p];
        int pb = (p > 0) ? spc[p - 1] : 0;
        for (int i = tid; i < PART; i += 256) { cnt_l[i] = 0; wsum[i] = 0.0f; }
        __syncthreads();
        const uint2* st = staging + (size_t)p * SCAP;
        for (int i = tid; i < m; i += 256) {
            uint2 v = st[i];
            int cl = v.x & 511;
            atomicAdd(&cnt_l[cl], 1);
            atomicAdd(&wsum[cl], __uint_as_float(v.y));
        }
        __syncthreads();
        for (int i = tid; i < PART; i += 256) sc[i] = cnt_l[i];
        __syncthreads();
        int i0 = tid, i1 = tid + 256;
#pragma unroll
        for (int d = 1; d < 512; d <<= 1) {
            int t0 = 0, t1 = 0;
            if (i0 < PART && i0 >= d) t0 = sc[i0 - d];
            if (i1 < PART && i1 >= d) t1 = sc[i1 - d];
            __syncthreads();
            if (i0 < PART) sc[i0] += t0;
            if (i1 < PART) sc[i1] += t1;
            __syncthreads();
        }
        for (int i = tid; i < PART; i += 256) {
            int n = p * PART + i;
            if (n < NN) {
                off[n] = pb + sc[i] - cnt_l[i];
                cntg[n] = cnt_l[i];
                dinv[n] = rsqrtf(1.0f + wsum[i]);
            }
        }
    } else {
        __shared__ float sW[32 * 32];
        __shared__ float sX[8 * 32];
        int base = (blockIdx.x - P) * 8;
        ((float4*)sW)[tid] = ((const float4*)W1)[tid];
        if (tid < 64) ((float4*)sX)[tid] = ((const float4*)(x + (size_t)base * 32))[tid];
        __syncthreads();
        int c = tid & 31, nl = tid >> 5;
        float acc = 0.0f;
#pragma unroll
        for (int k = 0; k < 32; ++k) acc = fmaf(sX[nl * 32 + k], sW[k * 32 + c], acc);
        h1[(size_t)(base + nl) * 32 + c] = f1fp8(acc);
    }
}

// ---------- phase 2b: write final normalized pairs, 4B packed (row<<15 | norm15) ----------
__global__ __launch_bounds__(512) void k_csr_b(const int* __restrict__ pcnt,
                                               const uint2* __restrict__ staging,
                                               const int* __restrict__ off,
                                               const float* __restrict__ dinv,
                                               unsigned* __restrict__ pairs) {
    __shared__ int cur[PART];
    __shared__ float sdc[PART];
    int p = blockIdx.x, tid = threadIdx.x;
    int m = pcnt[p];
    const uint2* st = staging + (size_t)p * SCAP;
    for (int i = tid; i < PART; i += 512) {
        int n = p * PART + i;
        cur[i] = (n < NN) ? off[n] : 0;
        sdc[i] = (n < NN) ? dinv[n] : 0.0f;
    }
    __syncthreads();
    for (int ib = tid; ib < m; ib += 512 * 4) {
        uint2 v[4];
        float dr[4];
#pragma unroll
        for (int j = 0; j < 4; ++j) {
            int i = ib + j * 512;
            if (i < m) v[j] = st[i];
        }
#pragma unroll
        for (int j = 0; j < 4; ++j) {
            int i = ib + j * 512;
            if (i < m) dr[j] = dinv[v[j].x >> 9];
        }
#pragma unroll
        for (int j = 0; j < 4; ++j) {
            int i = ib + j * 512;
            if (i < m) {
                int cl = v[j].x & 511;
                int pos = atomicAdd(&cur[cl], 1);
                float y = dr[j] * __uint_as_float(v[j].y) * sdc[cl];
                unsigned q = (unsigned)__float2int_rn(y * 32768.0f);
                q = min(q, 32767u);
                pairs[pos] = ((v[j].x >> 9) << 15) | q;
            }
        }
    }
}

// ---------- gather (fp8 h, 4B pairs): MODE 0 = fuse next GEMM, MODE 1 = bf16 relu out ----------
#define NM_SCALE 3.0517578125e-5f  // 1/32768
template <int MODE>
__global__ __launch_bounds__(256) void k_gather(const unsigned char* __restrict__ hb,
                                                const int* __restrict__ off,
                                                const int* __restrict__ cntg,
                                                const float* __restrict__ dinv,
                                                const unsigned* __restrict__ pairs,
                                                const float* __restrict__ bias,
                                                const float* __restrict__ Wn,
                                                unsigned char* __restrict__ hout,
                                                unsigned short* __restrict__ h3out) {
    __shared__ float sW[32 * 32];
    __shared__ float srow[32 * 33];
    int tid = threadIdx.x;
    if (MODE == 0) ((float4*)sW)[tid] = ((const float4*)Wn)[tid];
    int t = blockIdx.x * 256 + tid;  // NN*8 exact
    int n = t >> 3, c4 = t & 7;
    int cn = cntg[n];
    const unsigned* pp = pairs + off[n];
    float di = dinv[n], sl = di * di;
    unsigned hu = *(const unsigned*)(hb + (size_t)n * 32 + c4 * 4);
    float4 hf = fp8x4f(hu);
    float4 acc = make_float4(sl * hf.x, sl * hf.y, sl * hf.z, sl * hf.w);
    int k = 0;
    for (; k + 8 <= cn; k += 8) {
        unsigned p[8];
#pragma unroll
        for (int j = 0; j < 8; ++j) p[j] = pp[k + j];
        unsigned v[8];
#pragma unroll
        for (int j = 0; j < 8; ++j)
            v[j] = *(const unsigned*)(hb + (size_t)(p[j] >> 15) * 32 + c4 * 4);
#pragma unroll
        for (int j = 0; j < 8; ++j) {
            float nm = (float)(p[j] & 32767u) * NM_SCALE;
            float4 f = fp8x4f(v[j]);
            acc.x = fmaf(nm, f.x, acc.x);
            acc.y = fmaf(nm, f.y, acc.y);
            acc.z = fmaf(nm, f.z, acc.z);
            acc.w = fmaf(nm, f.w, acc.w);
        }
    }
    for (; k + 4 <= cn; k += 4) {
        unsigned p[4];
#pragma unroll
        for (int j = 0; j < 4; ++j) p[j] = pp[k + j];
        unsigned v[4];
#pragma unroll
        for (int j = 0; j < 4; ++j)
            v[j] = *(const unsigned*)(hb + (size_t)(p[j] >> 15) * 32 + c4 * 4);
#pragma unroll
        for (int j = 0; j < 4; ++j) {
            float nm = (float)(p[j] & 32767u) * NM_SCALE;
            float4 f = fp8x4f(v[j]);
            acc.x = fmaf(nm, f.x, acc.x);
            acc.y = fmaf(nm, f.y, acc.y);
            acc.z = fmaf(nm, f.z, acc.z);
            acc.w = fmaf(nm, f.w, acc.w);
        }
    }
    for (; k < cn; ++k) {
        unsigned p = pp[k];
        unsigned v = *(const unsigned*)(hb + (size_t)(p >> 15) * 32 + c4 * 4);
        float nm = (float)(p & 32767u) * NM_SCALE;
        float4 f = fp8x4f(v);
        acc.x = fmaf(nm, f.x, acc.x);
        acc.y = fmaf(nm, f.y, acc.y);
        acc.z = fmaf(nm, f.z, acc.z);
        acc.w = fmaf(nm, f.w, acc.w);
    }
    int cb = c4 * 4;
    if (MODE == 0) {
        int ln = tid >> 3;
        srow[ln * 33 + cb + 0] = fmaxf(acc.x + bias[cb + 0], 0.0f);
        srow[ln * 33 + cb + 1] = fmaxf(acc.y + bias[cb + 1], 0.0f);
        srow[ln * 33 + cb + 2] = fmaxf(acc.z + bias[cb + 2], 0.0f);
        srow[ln * 33 + cb + 3] = fmaxf(acc.w + bias[cb + 3], 0.0f);
        __syncthreads();
        const float* rw = srow + ln * 33;
        float o0 = 0.f, o1 = 0.f, o2 = 0.f, o3 = 0.f;
#pragma unroll
        for (int kk = 0; kk < 32; ++kk) {
            float r = rw[kk];
            const float* wr = sW + kk * 32 + cb;
            o0 = fmaf(r, wr[0], o0);
            o1 = fmaf(r, wr[1], o1);
            o2 = fmaf(r, wr[2], o2);
            o3 = fmaf(r, wr[3], o3);
        }
        *(unsigned*)(hout + (size_t)n * 32 + cb) = f4fp8(o0, o1, o2, o3);
    } else {
        ushort4 ou;
        ou.x = f2bf(fmaxf(acc.x + bias[cb + 0], 0.0f));
        ou.y = f2bf(fmaxf(acc.y + bias[cb + 1], 0.0f));
        ou.z = f2bf(fmaxf(acc.z + bias[cb + 2], 0.0f));
        ou.w = f2bf(fmaxf(acc.w + bias[cb + 3], 0.0f));
        *((ushort4*)(h3out + (size_t)n * 32) + c4) = ou;
    }
}

// ---------- global mean pool (bf16 in, already relu+bias) + head + log_softmax ----------
__global__ __launch_bounds__(1024) void k_pool_head(const unsigned short* __restrict__ h3,
                                                    const int* __restrict__ batch,
                                                    const float* __restrict__ Wout,
                                                    const float* __restrict__ bout,
                                                    float* __restrict__ out) {
    int g = blockIdx.x;
    __shared__ int sb[2];
    if (threadIdx.x == 0) {
        int lo = 0, hi = NN;
        while (lo < hi) { int m = (lo + hi) >> 1; if (batch[m] < g) lo = m + 1; else hi = m; }
        sb[0] = lo;
        lo = 0; hi = NN;
        while (lo < hi) { int m = (lo + hi) >> 1; if (batch[m] < g + 1) lo = m + 1; else hi = m; }
        sb[1] = lo;
    }
    __syncthreads();
    int start = sb[0], end = sb[1];
    int c = threadIdx.x & 31, grp = threadIdx.x >> 5;
    float acc = 0.0f;
    for (int n = start + grp; n < end; n += 32)
        acc += bf2f(h3[(size_t)n * 32 + c]);
    __shared__ float red[32 * 32];
    red[grp * 32 + c] = acc;
    __syncthreads();
    __shared__ float pooled[32];
    if (threadIdx.x < 32) {
        float s = 0.0f;
#pragma unroll
        for (int gr = 0; gr < 32; ++gr) s += red[gr * 32 + threadIdx.x];
        pooled[threadIdx.x] = s / fmaxf((float)(end - start), 1.0f);
    }
    __syncthreads();
    __shared__ float slog[8];
    if (threadIdx.x < 8) {
        float l = bout[threadIdx.x];
#pragma unroll
        for (int k = 0; k < 32; ++k) l = fmaf(pooled[k], Wout[k * 8 + threadIdx.x], l);
        slog[threadIdx.x] = l;
    }
    __syncthreads();
    if (threadIdx.x < 8) {
        float m = slog[0];
#pragma unroll
        for (int i = 1; i < 8; ++i) m = fmaxf(m, slog[i]);
        float s = 0.0f;
#pragma unroll
        for (int i = 0; i < 8; ++i) s += expf(slog[i] - m);
        out[g * NC + threadIdx.x] = slog[threadIdx.x] - m - logf(s);
    }
}

extern "C" void kernel_launch(void* const* d_in, const int* in_sizes, int n_in,
                              void* d_out, int out_size, void* d_ws, size_t ws_size,
                              hipStream_t stream) {
    const float* x     = (const float*)d_in[0];
    const int*   eidx  = (const int*)d_in[1];
    const float* ew    = (const float*)d_in[2];
    const int*   batch = (const int*)d_in[3];
    const float* W1 = (const float*)d_in[4];
    const float* b1 = (const float*)d_in[5];
    const float* W2 = (const float*)d_in[6];
    const float* b2 = (const float*)d_in[7];
    const float* W3 = (const float*)d_in[8];
    const float* b3 = (const float*)d_in[9];
    const float* Wout = (const float*)d_in[10];
    const float* bout = (const float*)d_in[11];
    float* out = (float*)d_out;

    const int* row = eidx;        // sources
    const int* col = eidx + NE;   // targets

    // layout: h1 fp8 | h2 fp8 | h3 bf16 | pairs(4B) | staging | dinv | off | cntg | pcnt (~35 MB)
    unsigned char* h1 = (unsigned char*)d_ws;                    // 3.2 MB
    unsigned char* h2 = h1 + (size_t)NN * HD;                    // 3.2 MB
    unsigned short* h3 = (unsigned short*)(h2 + (size_t)NN * HD);// 6.4 MB
    unsigned* pairs = (unsigned*)(h3 + (size_t)NN * HD);         // 6.4 MB
    uint2* staging = (uint2*)(pairs + NE);                       // 14.3 MB
    float* dinv = (float*)(staging + (size_t)P * SCAP);          // 0.4 MB
    int* off  = (int*)(dinv + NN);                               // 0.4 MB
    int* cntg = off + NN;                                        // 0.4 MB
    int* pcnt = cntg + NN;                                       // 1 KB

    hipMemsetAsync(pcnt, 0, P * sizeof(int), stream);
    k_bin<<<NBIN, 1024, 0, stream>>>(row, col, ew, pcnt, staging);
    k_csrA_gemm0<<<P + GEMM0_BLOCKS, 256, 0, stream>>>(pcnt, staging, off, cntg, dinv,
                                                       x, W1, h1);
    k_csr_b<<<P, 512, 0, stream>>>(pcnt, staging, off, dinv, pairs);
    k_gather<0><<<NORM_BLOCKS, 256, 0, stream>>>(h1, off, cntg, dinv, pairs, b1, W2,
                                                 h2, nullptr);
    k_gather<0><<<NORM_BLOCKS, 256, 0, stream>>>(h2, off, cntg, dinv, pairs, b2, W3,
                                                 h1, nullptr);
    k_gather<1><<<NORM_BLOCKS, 256, 0, stream>>>(h1, off, cntg, dinv, pairs, b3, nullptr,
                                                 nullptr, h3);
    k_pool_head<<<NG, 1024, 0, stream>>>(h3, batch, Wout, bout, out);
}

// Round 16
// 126.222 us; speedup vs baseline: 2.2741x; 1.0631x over previous
//
#include <hip/hip_runtime.h>
#include <math.h>

#define NN 100000
#define NE 1600000
#define HD 32
#define NG 64
#define NC 8

#define P 256        // partitions
#define PART 391     // nodes per partition; 391*256 = 100096 >= NN
#define SCAP 7000    // staging capacity per partition (Poisson(6250), +9 sigma)
#define CH 8192      // edges per k_bin block
#define NBIN ((NE + CH - 1) / CH)     // 196
#define GEMM0_BLOCKS32 (NN / 32)      // 3125 (32 nodes/block @1024 thr)
#define NORM_BLOCKS (NN * 8 / 256)    // 3125 (gather grid)

__device__ __forceinline__ float bf2f(unsigned short u) {
    return __uint_as_float(((unsigned int)u) << 16);
}
__device__ __forceinline__ unsigned short f2bf(float f) {
    unsigned int b = __float_as_uint(f);
    b = (b + 0x7FFFu + ((b >> 16) & 1u)) >> 16;  // RNE
    return (unsigned short)b;
}

// ---- fp8 helpers: hardware cvt if available, manual e4m3 fallback ----
#if __has_builtin(__builtin_amdgcn_cvt_pk_f32_fp8) && __has_builtin(__builtin_amdgcn_cvt_pk_fp8_f32)
#define FP8_HW 1
#else
#define FP8_HW 0
#endif

__device__ __forceinline__ float e4m3f_sw(unsigned u) {
    unsigned code = u & 0x7fu;
    unsigned e = code >> 3;
    float v;
    if (e == 0) v = (float)code * 0.001953125f;
    else v = __uint_as_float(((e + 120u) << 23) | ((code & 7u) << 20));
    return (u & 0x80u) ? -v : v;
}
__device__ __forceinline__ unsigned f2e4m3_sw(float f) {
    unsigned s = (__float_as_uint(f) >> 31) << 7;
    float a = fminf(fabsf(f), 448.0f);
    unsigned code;
    if (a >= 0.015625f) {
        unsigned x = __float_as_uint(a);
        x += 0x0007FFFFu + ((x >> 20) & 1u);
        code = (((x >> 23) - 120u) << 3) | ((x >> 20) & 7u);
    } else {
        code = (unsigned)__float2int_rn(a * 512.0f);
    }
    return s | code;
}

__device__ __forceinline__ float4 fp8x4f(unsigned v) {
#if FP8_HW
    using floatx2 = __attribute__((ext_vector_type(2))) float;
    floatx2 lo = __builtin_amdgcn_cvt_pk_f32_fp8((int)v, false);
    floatx2 hi = __builtin_amdgcn_cvt_pk_f32_fp8((int)v, true);
    return make_float4(lo[0], lo[1], hi[0], hi[1]);
#else
    return make_float4(e4m3f_sw(v & 255), e4m3f_sw((v >> 8) & 255),
                       e4m3f_sw((v >> 16) & 255), e4m3f_sw(v >> 24));
#endif
}
__device__ __forceinline__ unsigned f4fp8(float a, float b, float c, float d) {
#if FP8_HW
    int pk = 0;
    pk = __builtin_amdgcn_cvt_pk_fp8_f32(a, b, pk, false);
    pk = __builtin_amdgcn_cvt_pk_fp8_f32(c, d, pk, true);
    return (unsigned)pk;
#else
    return f2e4m3_sw(a) | (f2e4m3_sw(b) << 8) | (f2e4m3_sw(c) << 16) | (f2e4m3_sw(d) << 24);
#endif
}

// ---------- phase 1: bin edges (196 blocks) || gemm0: htmp = bf16(x@W1) (3125 blocks) ----------
__global__ __launch_bounds__(1024) void k_bin_gemm0(const int* __restrict__ row,
                                                    const int* __restrict__ col,
                                                    const float* __restrict__ w,
                                                    int* __restrict__ pcnt,
                                                    uint2* __restrict__ staging,
                                                    const float* __restrict__ x,
                                                    const float* __restrict__ W1,
                                                    unsigned short* __restrict__ htmp) {
    int tid = threadIdx.x;
    if (blockIdx.x < NBIN) {
        __shared__ int hist[P];
        __shared__ int base_[P];
        int e0 = blockIdx.x * CH;
        int nrem = min(CH, NE - e0);
        if (tid < P) hist[tid] = 0;
        __syncthreads();
        for (int i = tid; i < nrem; i += 1024)
            atomicAdd(&hist[(unsigned)col[e0 + i] / PART], 1);
        __syncthreads();
        if (tid < P) {
            int h = hist[tid];
            base_[tid] = h ? atomicAdd(&pcnt[tid], h) : 0;
            hist[tid] = 0;
        }
        __syncthreads();
        for (int i = tid; i < nrem; i += 1024) {
            int c = col[e0 + i];  // L2-hot re-read of own chunk
            int p = (unsigned)c / PART;
            int pos = base_[p] + atomicAdd(&hist[p], 1);
            uint2 v;
            v.x = (unsigned)(c - p * PART) | ((unsigned)row[e0 + i] << 9);
            v.y = __float_as_uint(w[e0 + i]);
            staging[(size_t)p * SCAP + pos] = v;
        }
    } else {
        __shared__ float sW[32 * 32];
        __shared__ float sX[32 * 32];
        int base = (blockIdx.x - NBIN) * 32;
        if (tid < 256) {
            ((float4*)sW)[tid] = ((const float4*)W1)[tid];
            ((float4*)sX)[tid] = ((const float4*)(x + (size_t)base * 32))[tid];
        }
        __syncthreads();
        int nl = tid >> 5, c = tid & 31;
        float acc = 0.0f;
#pragma unroll
        for (int k = 0; k < 32; ++k) acc = fmaf(sX[nl * 32 + k], sW[k * 32 + c], acc);
        htmp[(size_t)(base + nl) * 32 + c] = f2bf(acc);
    }
}

// ---------- phase 2: full CSR build (fused): counts+wsum -> scan -> dinv
//            -> h1 = fp8(dinv*htmp) -> pairs = (row<<15 | q15(w))  ----------
__global__ __launch_bounds__(512) void k_csr(const int* __restrict__ pcnt,
                                             const uint2* __restrict__ staging,
                                             int* __restrict__ off,
                                             int* __restrict__ cntg,
                                             float* __restrict__ dinv,
                                             const unsigned short* __restrict__ htmp,
                                             unsigned char* __restrict__ h1,
                                             unsigned* __restrict__ pairs) {
    __shared__ int spc[P];
    __shared__ int cnt_l[PART];
    __shared__ float wsum[PART];
    __shared__ int sc[PART];
    __shared__ float sdc[PART];
    __shared__ int cur[PART];
    int p = blockIdx.x, tid = threadIdx.x;
    if (tid < P) spc[tid] = pcnt[tid];
    __syncthreads();
#pragma unroll
    for (int d = 1; d < P; d <<= 1) {
        int t = 0;
        if (tid < P && tid >= d) t = spc[tid - d];
        __syncthreads();
        if (tid < P) spc[tid] += t;
        __syncthreads();
    }
    int m = pcnt[p];
    int pb = (p > 0) ? spc[p - 1] : 0;
    for (int i = tid; i < PART; i += 512) { cnt_l[i] = 0; wsum[i] = 0.0f; }
    __syncthreads();
    const uint2* st = staging + (size_t)p * SCAP;
    for (int i = tid; i < m; i += 512) {
        uint2 v = st[i];
        int cl = v.x & 511;
        atomicAdd(&cnt_l[cl], 1);
        atomicAdd(&wsum[cl], __uint_as_float(v.y));
    }
    __syncthreads();
    for (int i = tid; i < PART; i += 512) sc[i] = cnt_l[i];
    __syncthreads();
#pragma unroll
    for (int d = 1; d < 512; d <<= 1) {
        int t = 0;
        if (tid < PART && tid >= d) t = sc[tid - d];
        __syncthreads();
        if (tid < PART) sc[tid] += t;
        __syncthreads();
    }
    for (int i = tid; i < PART; i += 512) {
        int excl = sc[i] - cnt_l[i];
        cur[i] = excl;
        float dv = rsqrtf(1.0f + wsum[i]);
        sdc[i] = dv;
        int n = p * PART + i;
        if (n < NN) {
            off[n] = pb + excl;
            cntg[n] = cnt_l[i];
            dinv[n] = dv;
        }
    }
    __syncthreads();
    // rescale h1' = fp8(dinv * htmp)  (partition-local, coalesced)
    for (int u = tid; u < PART * 8; u += 512) {
        int i = u >> 3, q = u & 7;
        int n = p * PART + i;
        if (n < NN) {
            ushort4 hv = *((const ushort4*)(htmp + (size_t)n * 32) + q);
            float dv = sdc[i];
            *(unsigned*)(h1 + (size_t)n * 32 + q * 4) =
                f4fp8(dv * bf2f(hv.x), dv * bf2f(hv.y), dv * bf2f(hv.z), dv * bf2f(hv.w));
        }
    }
    // fill pairs (staging slab is L2-warm from the count pass)
    unsigned* pr = pairs + pb;
    for (int ib = tid; ib < m; ib += 512 * 4) {
        uint2 v[4];
#pragma unroll
        for (int j = 0; j < 4; ++j) {
            int i = ib + j * 512;
            if (i < m) v[j] = st[i];
        }
#pragma unroll
        for (int j = 0; j < 4; ++j) {
            int i = ib + j * 512;
            if (i < m) {
                int cl = v[j].x & 511;
                int pos = atomicAdd(&cur[cl], 1);
                unsigned q = (unsigned)__float2int_rn(__uint_as_float(v[j].y) * 32768.0f);
                q = min(q, 32767u);
                pr[pos] = ((v[j].x >> 9) << 15) | q;
            }
        }
    }
}

// ---------- gather on h' (fp8): agg = di*(h'[n] + sum w*h'[r]) ----------
// MODE 0: hout = fp8( di * (relu(agg + bias) @ Wn) )   MODE 1: h3 = bf16(relu(agg + b3))
#define NM_SCALE 3.0517578125e-5f  // 1/32768
template <int MODE>
__global__ __launch_bounds__(256) void k_gather(const unsigned char* __restrict__ hb,
                                                const int* __restrict__ off,
                                                const int* __restrict__ cntg,
                                                const float* __restrict__ dinv,
                                                const unsigned* __restrict__ pairs,
                                                const float* __restrict__ bias,
                                                const float* __restrict__ Wn,
                                                unsigned char* __restrict__ hout,
                                                unsigned short* __restrict__ h3out) {
    __shared__ float sW[32 * 32];
    __shared__ float srow[32 * 33];
    int tid = threadIdx.x;
    if (MODE == 0) ((float4*)sW)[tid] = ((const float4*)Wn)[tid];
    int t = blockIdx.x * 256 + tid;  // NN*8 exact
    int n = t >> 3, c4 = t & 7;
    int cn = cntg[n];
    const unsigned* pp = pairs + off[n];
    float di = dinv[n];
    unsigned hu = *(const unsigned*)(hb + (size_t)n * 32 + c4 * 4);
    float4 acc = fp8x4f(hu);  // self term, coefficient 1
    int k = 0;
    for (; k + 8 <= cn; k += 8) {
        unsigned p[8];
#pragma unroll
        for (int j = 0; j < 8; ++j) p[j] = pp[k + j];
        unsigned v[8];
#pragma unroll
        for (int j = 0; j < 8; ++j)
            v[j] = *(const unsigned*)(hb + (size_t)(p[j] >> 15) * 32 + c4 * 4);
#pragma unroll
        for (int j = 0; j < 8; ++j) {
            float nm = (float)(p[j] & 32767u) * NM_SCALE;
            float4 f = fp8x4f(v[j]);
            acc.x = fmaf(nm, f.x, acc.x);
            acc.y = fmaf(nm, f.y, acc.y);
            acc.z = fmaf(nm, f.z, acc.z);
            acc.w = fmaf(nm, f.w, acc.w);
        }
    }
    for (; k + 4 <= cn; k += 4) {
        unsigned p[4];
#pragma unroll
        for (int j = 0; j < 4; ++j) p[j] = pp[k + j];
        unsigned v[4];
#pragma unroll
        for (int j = 0; j < 4; ++j)
            v[j] = *(const unsigned*)(hb + (size_t)(p[j] >> 15) * 32 + c4 * 4);
#pragma unroll
        for (int j = 0; j < 4; ++j) {
            float nm = (float)(p[j] & 32767u) * NM_SCALE;
            float4 f = fp8x4f(v[j]);
            acc.x = fmaf(nm, f.x, acc.x);
            acc.y = fmaf(nm, f.y, acc.y);
            acc.z = fmaf(nm, f.z, acc.z);
            acc.w = fmaf(nm, f.w, acc.w);
        }
    }
    for (; k < cn; ++k) {
        unsigned p = pp[k];
        unsigned v = *(const unsigned*)(hb + (size_t)(p >> 15) * 32 + c4 * 4);
        float nm = (float)(p & 32767u) * NM_SCALE;
        float4 f = fp8x4f(v);
        acc.x = fmaf(nm, f.x, acc.x);
        acc.y = fmaf(nm, f.y, acc.y);
        acc.z = fmaf(nm, f.z, acc.z);
        acc.w = fmaf(nm, f.w, acc.w);
    }
    int cb = c4 * 4;
    if (MODE == 0) {
        int ln = tid >> 3;
        srow[ln * 33 + cb + 0] = fmaxf(fmaf(di, acc.x, bias[cb + 0]), 0.0f);
        srow[ln * 33 + cb + 1] = fmaxf(fmaf(di, acc.y, bias[cb + 1]), 0.0f);
        srow[ln * 33 + cb + 2] = fmaxf(fmaf(di, acc.z, bias[cb + 2]), 0.0f);
        srow[ln * 33 + cb + 3] = fmaxf(fmaf(di, acc.w, bias[cb + 3]), 0.0f);
        __syncthreads();
        const float* rw = srow + ln * 33;
        float o0 = 0.f, o1 = 0.f, o2 = 0.f, o3 = 0.f;
#pragma unroll
        for (int kk = 0; kk < 32; ++kk) {
            float r = rw[kk];
            const float* wr = sW + kk * 32 + cb;
            o0 = fmaf(r, wr[0], o0);
            o1 = fmaf(r, wr[1], o1);
            o2 = fmaf(r, wr[2], o2);
            o3 = fmaf(r, wr[3], o3);
        }
        *(unsigned*)(hout + (size_t)n * 32 + cb) = f4fp8(di * o0, di * o1, di * o2, di * o3);
    } else {
        ushort4 ou;
        ou.x = f2bf(fmaxf(fmaf(di, acc.x, bias[cb + 0]), 0.0f));
        ou.y = f2bf(fmaxf(fmaf(di, acc.y, bias[cb + 1]), 0.0f));
        ou.z = f2bf(fmaxf(fmaf(di, acc.z, bias[cb + 2]), 0.0f));
        ou.w = f2bf(fmaxf(fmaf(di, acc.w, bias[cb + 3]), 0.0f));
        *((ushort4*)(h3out + (size_t)n * 32) + c4) = ou;
    }
}

// ---------- global mean pool (bf16 in, already relu+bias) + head + log_softmax ----------
__global__ __launch_bounds__(1024) void k_pool_head(const unsigned short* __restrict__ h3,
                                                    const int* __restrict__ batch,
                                                    const float* __restrict__ Wout,
                                                    const float* __restrict__ bout,
                                                    float* __restrict__ out) {
    int g = blockIdx.x;
    __shared__ int sb[2];
    if (threadIdx.x == 0) {
        int lo = 0, hi = NN;
        while (lo < hi) { int m = (lo + hi) >> 1; if (batch[m] < g) lo = m + 1; else hi = m; }
        sb[0] = lo;
        lo = 0; hi = NN;
        while (lo < hi) { int m = (lo + hi) >> 1; if (batch[m] < g + 1) lo = m + 1; else hi = m; }
        sb[1] = lo;
    }
    __syncthreads();
    int start = sb[0], end = sb[1];
    int c = threadIdx.x & 31, grp = threadIdx.x >> 5;
    float acc = 0.0f;
    for (int n = start + grp; n < end; n += 32)
        acc += bf2f(h3[(size_t)n * 32 + c]);
    __shared__ float red[32 * 32];
    red[grp * 32 + c] = acc;
    __syncthreads();
    __shared__ float pooled[32];
    if (threadIdx.x < 32) {
        float s = 0.0f;
#pragma unroll
        for (int gr = 0; gr < 32; ++gr) s += red[gr * 32 + threadIdx.x];
        pooled[threadIdx.x] = s / fmaxf((float)(end - start), 1.0f);
    }
    __syncthreads();
    __shared__ float slog[8];
    if (threadIdx.x < 8) {
        float l = bout[threadIdx.x];
#pragma unroll
        for (int k = 0; k < 32; ++k) l = fmaf(pooled[k], Wout[k * 8 + threadIdx.x], l);
        slog[threadIdx.x] = l;
    }
    __syncthreads();
    if (threadIdx.x < 8) {
        float m = slog[0];
#pragma unroll
        for (int i = 1; i < 8; ++i) m = fmaxf(m, slog[i]);
        float s = 0.0f;
#pragma unroll
        for (int i = 0; i < 8; ++i) s += expf(slog[i] - m);
        out[g * NC + threadIdx.x] = slog[threadIdx.x] - m - logf(s);
    }
}

extern "C" void kernel_launch(void* const* d_in, const int* in_sizes, int n_in,
                              void* d_out, int out_size, void* d_ws, size_t ws_size,
                              hipStream_t stream) {
    const float* x     = (const float*)d_in[0];
    const int*   eidx  = (const int*)d_in[1];
    const float* ew    = (const float*)d_in[2];
    const int*   batch = (const int*)d_in[3];
    const float* W1 = (const float*)d_in[4];
    const float* b1 = (const float*)d_in[5];
    const float* W2 = (const float*)d_in[6];
    const float* b2 = (const float*)d_in[7];
    const float* W3 = (const float*)d_in[8];
    const float* b3 = (const float*)d_in[9];
    const float* Wout = (const float*)d_in[10];
    const float* bout = (const float*)d_in[11];
    float* out = (float*)d_out;

    const int* row = eidx;        // sources
    const int* col = eidx + NE;   // targets

    // layout: h1 fp8 | h2 fp8 | h3/htmp bf16 | pairs(4B) | staging | dinv | off | cntg | pcnt
    unsigned char* h1 = (unsigned char*)d_ws;                    // 3.2 MB
    unsigned char* h2 = h1 + (size_t)NN * HD;                    // 3.2 MB
    unsigned short* h3 = (unsigned short*)(h2 + (size_t)NN * HD);// 6.4 MB (htmp during build)
    unsigned* pairs = (unsigned*)(h3 + (size_t)NN * HD);         // 6.4 MB
    uint2* staging = (uint2*)(pairs + NE);                       // 14.3 MB
    float* dinv = (float*)(staging + (size_t)P * SCAP);          // 0.4 MB
    int* off  = (int*)(dinv + NN);                               // 0.4 MB
    int* cntg = off + NN;                                        // 0.4 MB
    int* pcnt = cntg + NN;                                       // 1 KB

    hipMemsetAsync(pcnt, 0, P * sizeof(int), stream);
    k_bin_gemm0<<<NBIN + GEMM0_BLOCKS32, 1024, 0, stream>>>(row, col, ew, pcnt, staging,
                                                            x, W1, h3 /*htmp*/);
    k_csr<<<P, 512, 0, stream>>>(pcnt, staging, off, cntg, dinv, h3 /*htmp*/, h1, pairs);
    k_gather<0><<<NORM_BLOCKS, 256, 0, stream>>>(h1, off, cntg, dinv, pairs, b1, W2,
                                                 h2, nullptr);
    k_gather<0><<<NORM_BLOCKS, 256, 0, stream>>>(h2, off, cntg, dinv, pairs, b2, W3,
                                                 h1, nullptr);
    k_gather<1><<<NORM_BLOCKS, 256, 0, stream>>>(h1, off, cntg, dinv, pairs, b3, nullptr,
                                                 nullptr, h3);
    k_pool_head<<<NG, 1024, 0, stream>>>(h3, batch, Wout, bout, out);
}

// Round 17
// 123.212 us; speedup vs baseline: 2.3297x; 1.0244x over previous
//
#include <hip/hip_runtime.h>
#include <math.h>

#define NN 100000
#define NE 1600000
#define HD 32
#define NG 64
#define NC 8

#define P 256        // partitions
#define PART 391     // nodes per partition; 391*256 = 100096 >= NN
#define SCAP 7000    // staging capacity per partition (Poisson(6250), +9 sigma)
#define CH 8192      // edges per k_bin block
#define NBIN ((NE + CH - 1) / CH)     // 196
#define GEMM0_BLOCKS32 (NN / 32)      // 3125 (32 nodes/block @1024 thr)
#define NORM_BLOCKS (NN * 8 / 256)    // 3125 (gather grid, 32 nodes/block)
#define CAPL 1024                     // LDS pairs-slice capacity (mean 512, sigma 23)

__device__ __forceinline__ float bf2f(unsigned short u) {
    return __uint_as_float(((unsigned int)u) << 16);
}
__device__ __forceinline__ unsigned short f2bf(float f) {
    unsigned int b = __float_as_uint(f);
    b = (b + 0x7FFFu + ((b >> 16) & 1u)) >> 16;  // RNE
    return (unsigned short)b;
}

// ---- fp8 helpers: hardware cvt if available, manual e4m3 fallback ----
#if __has_builtin(__builtin_amdgcn_cvt_pk_f32_fp8) && __has_builtin(__builtin_amdgcn_cvt_pk_fp8_f32)
#define FP8_HW 1
#else
#define FP8_HW 0
#endif

__device__ __forceinline__ float e4m3f_sw(unsigned u) {
    unsigned code = u & 0x7fu;
    unsigned e = code >> 3;
    float v;
    if (e == 0) v = (float)code * 0.001953125f;
    else v = __uint_as_float(((e + 120u) << 23) | ((code & 7u) << 20));
    return (u & 0x80u) ? -v : v;
}
__device__ __forceinline__ unsigned f2e4m3_sw(float f) {
    unsigned s = (__float_as_uint(f) >> 31) << 7;
    float a = fminf(fabsf(f), 448.0f);
    unsigned code;
    if (a >= 0.015625f) {
        unsigned x = __float_as_uint(a);
        x += 0x0007FFFFu + ((x >> 20) & 1u);
        code = (((x >> 23) - 120u) << 3) | ((x >> 20) & 7u);
    } else {
        code = (unsigned)__float2int_rn(a * 512.0f);
    }
    return s | code;
}

__device__ __forceinline__ float4 fp8x4f(unsigned v) {
#if FP8_HW
    using floatx2 = __attribute__((ext_vector_type(2))) float;
    floatx2 lo = __builtin_amdgcn_cvt_pk_f32_fp8((int)v, false);
    floatx2 hi = __builtin_amdgcn_cvt_pk_f32_fp8((int)v, true);
    return make_float4(lo[0], lo[1], hi[0], hi[1]);
#else
    return make_float4(e4m3f_sw(v & 255), e4m3f_sw((v >> 8) & 255),
                       e4m3f_sw((v >> 16) & 255), e4m3f_sw(v >> 24));
#endif
}
__device__ __forceinline__ unsigned f4fp8(float a, float b, float c, float d) {
#if FP8_HW
    int pk = 0;
    pk = __builtin_amdgcn_cvt_pk_fp8_f32(a, b, pk, false);
    pk = __builtin_amdgcn_cvt_pk_fp8_f32(c, d, pk, true);
    return (unsigned)pk;
#else
    return f2e4m3_sw(a) | (f2e4m3_sw(b) << 8) | (f2e4m3_sw(c) << 16) | (f2e4m3_sw(d) << 24);
#endif
}

// ---------- phase 1: bin edges (196 blocks) || gemm0: htmp = bf16(x@W1) (3125 blocks) ----------
__global__ __launch_bounds__(1024) void k_bin_gemm0(const int* __restrict__ row,
                                                    const int* __restrict__ col,
                                                    const float* __restrict__ w,
                                                    int* __restrict__ pcnt,
                                                    uint2* __restrict__ staging,
                                                    const float* __restrict__ x,
                                                    const float* __restrict__ W1,
                                                    unsigned short* __restrict__ htmp) {
    int tid = threadIdx.x;
    if (blockIdx.x < NBIN) {
        __shared__ int scol[CH];   // 32 KB (1024-thr blocks are thread-capped at 2/CU anyway)
        __shared__ int hist[P];
        __shared__ int base_[P];
        int e0 = blockIdx.x * CH;
        int nrem = min(CH, NE - e0);
        if (tid < P) hist[tid] = 0;
        __syncthreads();
        for (int i = tid; i < nrem; i += 1024) {
            int c = col[e0 + i];
            scol[i] = c;
            atomicAdd(&hist[(unsigned)c / PART], 1);
        }
        __syncthreads();
        if (tid < P) {
            int h = hist[tid];
            base_[tid] = h ? atomicAdd(&pcnt[tid], h) : 0;
            hist[tid] = 0;
        }
        __syncthreads();
        for (int i = tid; i < nrem; i += 1024) {
            int c = scol[i];
            int p = (unsigned)c / PART;
            int pos = base_[p] + atomicAdd(&hist[p], 1);
            uint2 v;
            v.x = (unsigned)(c - p * PART) | ((unsigned)row[e0 + i] << 9);
            v.y = __float_as_uint(w[e0 + i]);
            staging[(size_t)p * SCAP + pos] = v;
        }
    } else {
        __shared__ float sW[32 * 32];
        __shared__ float sX[32 * 32];
        int base = (blockIdx.x - NBIN) * 32;
        if (tid < 256) {
            ((float4*)sW)[tid] = ((const float4*)W1)[tid];
            ((float4*)sX)[tid] = ((const float4*)(x + (size_t)base * 32))[tid];
        }
        __syncthreads();
        int nl = tid >> 5, c = tid & 31;
        float acc = 0.0f;
#pragma unroll
        for (int k = 0; k < 32; ++k) acc = fmaf(sX[nl * 32 + k], sW[k * 32 + c], acc);
        htmp[(size_t)(base + nl) * 32 + c] = f2bf(acc);
    }
}

// ---------- phase 2: fused CSR build: counts+wsum -> scan -> dinv
//            -> h1 = fp8(dinv*htmp) -> pairs = (row<<15 | q15(w)) ----------
__global__ __launch_bounds__(512) void k_csr(const int* __restrict__ pcnt,
                                             const uint2* __restrict__ staging,
                                             int* __restrict__ off,
                                             int* __restrict__ cntg,
                                             float* __restrict__ dinv,
                                             const unsigned short* __restrict__ htmp,
                                             unsigned char* __restrict__ h1,
                                             unsigned* __restrict__ pairs) {
    __shared__ int spc[P];
    __shared__ int cnt_l[PART];
    __shared__ float wsum[PART];
    __shared__ int sc[PART];
    __shared__ float sdc[PART];
    __shared__ int cur[PART];
    int p = blockIdx.x, tid = threadIdx.x;
    if (tid < P) spc[tid] = pcnt[tid];
    __syncthreads();
#pragma unroll
    for (int d = 1; d < P; d <<= 1) {
        int t = 0;
        if (tid < P && tid >= d) t = spc[tid - d];
        __syncthreads();
        if (tid < P) spc[tid] += t;
        __syncthreads();
    }
    int m = pcnt[p];
    int pb = (p > 0) ? spc[p - 1] : 0;
    if (p == P - 1 && tid == 0) off[NN] = pb + m;  // sentinel (upper buckets empty)
    for (int i = tid; i < PART; i += 512) { cnt_l[i] = 0; wsum[i] = 0.0f; }
    __syncthreads();
    const uint2* st = staging + (size_t)p * SCAP;
    for (int i = tid; i < m; i += 512) {
        uint2 v = st[i];
        int cl = v.x & 511;
        atomicAdd(&cnt_l[cl], 1);
        atomicAdd(&wsum[cl], __uint_as_float(v.y));
    }
    __syncthreads();
    for (int i = tid; i < PART; i += 512) sc[i] = cnt_l[i];
    __syncthreads();
#pragma unroll
    for (int d = 1; d < 512; d <<= 1) {
        int t = 0;
        if (tid < PART && tid >= d) t = sc[tid - d];
        __syncthreads();
        if (tid < PART) sc[tid] += t;
        __syncthreads();
    }
    for (int i = tid; i < PART; i += 512) {
        int excl = sc[i] - cnt_l[i];
        cur[i] = excl;
        float dv = rsqrtf(1.0f + wsum[i]);
        sdc[i] = dv;
        int n = p * PART + i;
        if (n < NN) {
            off[n] = pb + excl;
            cntg[n] = cnt_l[i];
            dinv[n] = dv;
        }
    }
    __syncthreads();
    // rescale h1' = fp8(dinv * htmp)  (partition-local, coalesced)
    for (int u = tid; u < PART * 8; u += 512) {
        int i = u >> 3, q = u & 7;
        int n = p * PART + i;
        if (n < NN) {
            ushort4 hv = *((const ushort4*)(htmp + (size_t)n * 32) + q);
            float dv = sdc[i];
            *(unsigned*)(h1 + (size_t)n * 32 + q * 4) =
                f4fp8(dv * bf2f(hv.x), dv * bf2f(hv.y), dv * bf2f(hv.z), dv * bf2f(hv.w));
        }
    }
    // fill pairs (staging slab is L2-warm from the count pass)
    unsigned* pr = pairs + pb;
    for (int ib = tid; ib < m; ib += 512 * 4) {
        uint2 v[4];
#pragma unroll
        for (int j = 0; j < 4; ++j) {
            int i = ib + j * 512;
            if (i < m) v[j] = st[i];
        }
#pragma unroll
        for (int j = 0; j < 4; ++j) {
            int i = ib + j * 512;
            if (i < m) {
                int cl = v[j].x & 511;
                int pos = atomicAdd(&cur[cl], 1);
                unsigned q = (unsigned)__float2int_rn(__uint_as_float(v[j].y) * 32768.0f);
                q = min(q, 32767u);
                pr[pos] = ((v[j].x >> 9) << 15) | q;
            }
        }
    }
}

// ---------- gather on h' (fp8), block pairs-slice staged in LDS ----------
// agg = di*(h'[n] + sum w*h'[r])
// MODE 0: hout = fp8( di * (relu(agg + bias) @ Wn) )   MODE 1: h3 = bf16(relu(agg + b3))
#define NM_SCALE 3.0517578125e-5f  // 1/32768

#define GBODY(PAIR_AT)                                                              \
    {                                                                               \
        int k = 0;                                                                  \
        for (; k + 8 <= cn; k += 8) {                                               \
            unsigned pw[8];                                                         \
            _Pragma("unroll") for (int j = 0; j < 8; ++j) pw[j] = PAIR_AT(k + j);   \
            unsigned hv[8];                                                         \
            _Pragma("unroll") for (int j = 0; j < 8; ++j)                           \
                hv[j] = *(const unsigned*)(hb + (size_t)(pw[j] >> 15) * 32 + c4 * 4);\
            _Pragma("unroll") for (int j = 0; j < 8; ++j) {                         \
                float nm = (float)(pw[j] & 32767u) * NM_SCALE;                      \
                float4 f = fp8x4f(hv[j]);                                           \
                acc.x = fmaf(nm, f.x, acc.x);                                       \
                acc.y = fmaf(nm, f.y, acc.y);                                       \
                acc.z = fmaf(nm, f.z, acc.z);                                       \
                acc.w = fmaf(nm, f.w, acc.w);                                       \
            }                                                                       \
        }                                                                           \
        for (; k + 4 <= cn; k += 4) {                                               \
            unsigned pw[4];                                                         \
            _Pragma("unroll") for (int j = 0; j < 4; ++j) pw[j] = PAIR_AT(k + j);   \
            unsigned hv[4];                                                         \
            _Pragma("unroll") for (int j = 0; j < 4; ++j)                           \
                hv[j] = *(const unsigned*)(hb + (size_t)(pw[j] >> 15) * 32 + c4 * 4);\
            _Pragma("unroll") for (int j = 0; j < 4; ++j) {                         \
                float nm = (float)(pw[j] & 32767u) * NM_SCALE;                      \
                float4 f = fp8x4f(hv[j]);                                           \
                acc.x = fmaf(nm, f.x, acc.x);                                       \
                acc.y = fmaf(nm, f.y, acc.y);                                       \
                acc.z = fmaf(nm, f.z, acc.z);                                       \
                acc.w = fmaf(nm, f.w, acc.w);                                       \
            }                                                                       \
        }                                                                           \
        for (; k < cn; ++k) {                                                       \
            unsigned pw = PAIR_AT(k);                                               \
            unsigned hv = *(const unsigned*)(hb + (size_t)(pw >> 15) * 32 + c4 * 4);\
            float nm = (float)(pw & 32767u) * NM_SCALE;                             \
            float4 f = fp8x4f(hv);                                                  \
            acc.x = fmaf(nm, f.x, acc.x);                                           \
            acc.y = fmaf(nm, f.y, acc.y);                                           \
            acc.z = fmaf(nm, f.z, acc.z);                                           \
            acc.w = fmaf(nm, f.w, acc.w);                                           \
        }                                                                           \
    }

#define SPAIR_AT(i) spair[l0 + (i)]
#define GPAIR_AT(i) pp[(i)]

template <int MODE>
__global__ __launch_bounds__(256) void k_gather(const unsigned char* __restrict__ hb,
                                                const int* __restrict__ off,
                                                const int* __restrict__ cntg,
                                                const float* __restrict__ dinv,
                                                const unsigned* __restrict__ pairs,
                                                const float* __restrict__ bias,
                                                const float* __restrict__ Wn,
                                                unsigned char* __restrict__ hout,
                                                unsigned short* __restrict__ h3out) {
    __shared__ float sW[32 * 32];
    __shared__ float srow[32 * 33];
    __shared__ unsigned spair[CAPL];
    int tid = threadIdx.x;
    if (MODE == 0) ((float4*)sW)[tid] = ((const float4*)Wn)[tid];
    int nb = blockIdx.x * 32;      // first node of this block
    int base = off[nb];
    int mb = off[nb + 32] - base;  // block's contiguous pairs-slice length
    int mbc = min(mb, CAPL);
    for (int i = tid; i < mbc; i += 256) spair[i] = pairs[base + i];
    __syncthreads();
    int t = blockIdx.x * 256 + tid;  // NN*8 exact
    int n = t >> 3, c4 = t & 7;
    int cn = cntg[n];
    int offn = off[n];
    int l0 = offn - base;
    const unsigned* pp = pairs + offn;
    float di = dinv[n];
    unsigned hu = *(const unsigned*)(hb + (size_t)n * 32 + c4 * 4);
    float4 acc = fp8x4f(hu);  // self term, coefficient 1
    if (l0 + cn <= CAPL) {
        GBODY(SPAIR_AT)
    } else {
        GBODY(GPAIR_AT)
    }
    int cb = c4 * 4;
    if (MODE == 0) {
        int ln = tid >> 3;
        srow[ln * 33 + cb + 0] = fmaxf(fmaf(di, acc.x, bias[cb + 0]), 0.0f);
        srow[ln * 33 + cb + 1] = fmaxf(fmaf(di, acc.y, bias[cb + 1]), 0.0f);
        srow[ln * 33 + cb + 2] = fmaxf(fmaf(di, acc.z, bias[cb + 2]), 0.0f);
        srow[ln * 33 + cb + 3] = fmaxf(fmaf(di, acc.w, bias[cb + 3]), 0.0f);
        __syncthreads();
        const float* rw = srow + ln * 33;
        float o0 = 0.f, o1 = 0.f, o2 = 0.f, o3 = 0.f;
#pragma unroll
        for (int kk = 0; kk < 32; ++kk) {
            float r = rw[kk];
            const float* wr = sW + kk * 32 + cb;
            o0 = fmaf(r, wr[0], o0);
            o1 = fmaf(r, wr[1], o1);
            o2 = fmaf(r, wr[2], o2);
            o3 = fmaf(r, wr[3], o3);
        }
        *(unsigned*)(hout + (size_t)n * 32 + cb) = f4fp8(di * o0, di * o1, di * o2, di * o3);
    } else {
        ushort4 ou;
        ou.x = f2bf(fmaxf(fmaf(di, acc.x, bias[cb + 0]), 0.0f));
        ou.y = f2bf(fmaxf(fmaf(di, acc.y, bias[cb + 1]), 0.0f));
        ou.z = f2bf(fmaxf(fmaf(di, acc.z, bias[cb + 2]), 0.0f));
        ou.w = f2bf(fmaxf(fmaf(di, acc.w, bias[cb + 3]), 0.0f));
        *((ushort4*)(h3out + (size_t)n * 32) + c4) = ou;
    }
}

// ---------- pool: 512 blocks (8 slices per graph) -> gsum/gcnt atomics ----------
__global__ __launch_bounds__(1024) void k_pool(const unsigned short* __restrict__ h3,
                                               const int* __restrict__ batch,
                                               float* __restrict__ gsum,
                                               float* __restrict__ gcnt) {
    int g = blockIdx.x >> 3, s = blockIdx.x & 7;
    __shared__ int sb[2];
    if (threadIdx.x == 0) {
        int lo = 0, hi = NN;
        while (lo < hi) { int m = (lo + hi) >> 1; if (batch[m] < g) lo = m + 1; else hi = m; }
        sb[0] = lo;
        lo = 0; hi = NN;
        while (lo < hi) { int m = (lo + hi) >> 1; if (batch[m] < g + 1) lo = m + 1; else hi = m; }
        sb[1] = lo;
    }
    __syncthreads();
    int start = sb[0], len = sb[1] - sb[0];
    int a = start + (int)((long long)len * s / 8);
    int b = start + (int)((long long)len * (s + 1) / 8);
    int c = threadIdx.x & 31, grp = threadIdx.x >> 5;
    float acc = 0.0f;
    for (int n = a + grp; n < b; n += 32)
        acc += bf2f(h3[(size_t)n * 32 + c]);
    __shared__ float red[32 * 32];
    red[grp * 32 + c] = acc;
    __syncthreads();
    if (threadIdx.x < 32) {
        float sum = 0.0f;
#pragma unroll
        for (int gr = 0; gr < 32; ++gr) sum += red[gr * 32 + threadIdx.x];
        if (sum != 0.0f) atomicAdd(&gsum[g * HD + threadIdx.x], sum);
    }
    if (threadIdx.x == 0 && b > a) atomicAdd(&gcnt[g], (float)(b - a));
}

// ---------- head: pooled = gsum/gcnt; logits = pooled@Wout+bout; log_softmax ----------
__global__ __launch_bounds__(256) void k_head(const float* __restrict__ gsum,
                                              const float* __restrict__ gcnt,
                                              const float* __restrict__ Wout,
                                              const float* __restrict__ bout,
                                              float* __restrict__ out) {
    __shared__ float pooled[NG * 33];
    __shared__ float sW[32 * NC];
    __shared__ float slog[NG * NC];
    int tid = threadIdx.x;
    sW[tid] = Wout[tid];  // 256 = 32*8
    for (int i = tid; i < NG * HD; i += 256) {
        int g = i >> 5, c = i & 31;
        pooled[g * 33 + c] = gsum[i] / fmaxf(gcnt[g], 1.0f);
    }
    __syncthreads();
    for (int i = tid; i < NG * NC; i += 256) {
        int g = i >> 3, c = i & 7;
        float l = bout[c];
        const float* pr = pooled + g * 33;
#pragma unroll
        for (int k = 0; k < 32; ++k) l = fmaf(pr[k], sW[k * NC + c], l);
        slog[i] = l;
    }
    __syncthreads();
    if (tid < NG) {
        const float* sl = slog + tid * NC;
        float m = sl[0];
#pragma unroll
        for (int i = 1; i < NC; ++i) m = fmaxf(m, sl[i]);
        float s = 0.0f;
#pragma unroll
        for (int i = 0; i < NC; ++i) s += expf(sl[i] - m);
        float lse = m + logf(s);
#pragma unroll
        for (int i = 0; i < NC; ++i) out[tid * NC + i] = sl[i] - lse;
    }
}

extern "C" void kernel_launch(void* const* d_in, const int* in_sizes, int n_in,
                              void* d_out, int out_size, void* d_ws, size_t ws_size,
                              hipStream_t stream) {
    const float* x     = (const float*)d_in[0];
    const int*   eidx  = (const int*)d_in[1];
    const float* ew    = (const float*)d_in[2];
    const int*   batch = (const int*)d_in[3];
    const float* W1 = (const float*)d_in[4];
    const float* b1 = (const float*)d_in[5];
    const float* W2 = (const float*)d_in[6];
    const float* b2 = (const float*)d_in[7];
    const float* W3 = (const float*)d_in[8];
    const float* b3 = (const float*)d_in[9];
    const float* Wout = (const float*)d_in[10];
    const float* bout = (const float*)d_in[11];
    float* out = (float*)d_out;

    const int* row = eidx;        // sources
    const int* col = eidx + NE;   // targets

    // layout: h1 fp8 | h2 fp8 | h3/htmp bf16 | pairs(4B) | staging | dinv | off(NN+1)
    //         | cntg | [pcnt | gsum | gcnt] (zeroed)
    unsigned char* h1 = (unsigned char*)d_ws;                    // 3.2 MB
    unsigned char* h2 = h1 + (size_t)NN * HD;                    // 3.2 MB
    unsigned short* h3 = (unsigned short*)(h2 + (size_t)NN * HD);// 6.4 MB (htmp during build)
    unsigned* pairs = (unsigned*)(h3 + (size_t)NN * HD);         // 6.4 MB
    uint2* staging = (uint2*)(pairs + NE);                       // 14.3 MB
    float* dinv = (float*)(staging + (size_t)P * SCAP);          // 0.4 MB
    int* off  = (int*)(dinv + NN);                               // NN+1 ints
    int* cntg = off + NN + 1;                                    // NN ints
    int* pcnt = cntg + NN;                                       // P ints
    float* gsum = (float*)(pcnt + P);                            // NG*HD
    float* gcnt = gsum + NG * HD;                                // NG

    hipMemsetAsync(pcnt, 0, (P + NG * HD + NG) * sizeof(int), stream);
    k_bin_gemm0<<<NBIN + GEMM0_BLOCKS32, 1024, 0, stream>>>(row, col, ew, pcnt, staging,
                                                            x, W1, h3 /*htmp*/);
    k_csr<<<P, 512, 0, stream>>>(pcnt, staging, off, cntg, dinv, h3 /*htmp*/, h1, pairs);
    k_gather<0><<<NORM_BLOCKS, 256, 0, stream>>>(h1, off, cntg, dinv, pairs, b1, W2,
                                                 h2, nullptr);
    k_gather<0><<<NORM_BLOCKS, 256, 0, stream>>>(h2, off, cntg, dinv, pairs, b2, W3,
                                                 h1, nullptr);
    k_gather<1><<<NORM_BLOCKS, 256, 0, stream>>>(h1, off, cntg, dinv, pairs, b3, nullptr,
                                                 nullptr, h3);
    k_pool<<<NG * 8, 1024, 0, stream>>>(h3, batch, gsum, gcnt);
    k_head<<<1, 256, 0, stream>>>(gsum, gcnt, Wout, bout, out);
}